// Round 1
// baseline (577.906 us; speedup 1.0000x reference)
//
#include <hip/hip_runtime.h>

// Problem constants (from reference):
//   B=16, P1=25, P2=24 -> S=600 tokens; E=(8,8,16)=1024; heads (2,2,4)=16, head_dim 4*4*4=64
#define S   600
#define NB  16
#define NH  16
#define HD  64
#define SCALE 0.125f   // (4*4*4)^-0.5

#define LDK 68   // Q/K/V LDS row stride (floats): 4*68=272B, 16B aligned, spreads banks
#define LDP 65   // P LDS row stride (scalar access only)
#define LDT 20   // TCL intermediate row stride (rows of 16): 80B aligned, spreads banks

__device__ __forceinline__ void dot4(float& a, const float4 q, const float4 k) {
  a = fmaf(q.x, k.x, a); a = fmaf(q.y, k.y, a);
  a = fmaf(q.z, k.z, a); a = fmaf(q.w, k.w, a);
}
__device__ __forceinline__ void fma4(float4& a, const float p, const float4 v) {
  a.x = fmaf(p, v.x, a.x); a.y = fmaf(p, v.y, a.y);
  a.z = fmaf(p, v.z, a.z); a.w = fmaf(p, v.w, a.w);
}

// ---------------------------------------------------------------------------
// Kernel A: TCL for q,k,v. One block per token. Output in head-split layout
// [b][h][t][dim] with h=(h1*2+h2)*4+h3, dim=x*16+y*4+z, where embed indices
// a=x*2+h1, c=y*2+h2, e2=z*4+h3 (matches reference reshape).
// ---------------------------------------------------------------------------
__global__ __launch_bounds__(256) void tcl_qkv_kernel(
    const float* __restrict__ x,
    const float* __restrict__ qw0, const float* __restrict__ qw1,
    const float* __restrict__ qw2, const float* __restrict__ qb,
    const float* __restrict__ kw0, const float* __restrict__ kw1,
    const float* __restrict__ kw2, const float* __restrict__ kb,
    const float* __restrict__ vw0, const float* __restrict__ vw1,
    const float* __restrict__ vw2, const float* __restrict__ vb,
    float* __restrict__ Qo, float* __restrict__ Ko, float* __restrict__ Vo)
{
  __shared__ __align__(16) float sx[1024];       // [x][y][z] natural
  __shared__ __align__(16) float t1[64 * LDT];   // rows of 16 padded to 20
  __shared__ __align__(16) float t2[64 * LDT];
  __shared__ float sw0[3][64], sw1[3][64], sw2[3][256];

  const int tid = threadIdx.x;
  const int t = blockIdx.x, b = blockIdx.y;
  const size_t tok = (size_t)b * S + t;

  *(float4*)&sx[tid * 4] = *(const float4*)&x[tok * 1024 + tid * 4];
  if (tid < 64) {
    sw0[0][tid] = qw0[tid]; sw0[1][tid] = kw0[tid]; sw0[2][tid] = vw0[tid];
    sw1[0][tid] = qw1[tid]; sw1[1][tid] = kw1[tid]; sw1[2][tid] = vw1[tid];
  }
  sw2[0][tid] = qw2[tid]; sw2[1][tid] = kw2[tid]; sw2[2][tid] = vw2[tid];
  __syncthreads();

  // compute mapping: thread -> (a, c, d-quad)
  const int a = tid >> 5, c = (tid >> 2) & 7, dq = tid & 3;
  // scatter mapping: thread -> (head, dim-quad)
  const int h = tid >> 4, dimq = tid & 15;
  const int xs = dimq >> 2, ys = dimq & 3;
  const int aa = 2 * xs + (h >> 3), cc = 2 * ys + ((h >> 2) & 1), h3 = h & 3;
  const int sb = (aa * 8 + cc) * LDT + h3;
  const size_t ooff = ((size_t)(b * NH + h) * S + t) * HD + dimq * 4;

  const float* biases[3] = {qb, kb, vb};
  float* outs[3] = {Qo, Ko, Vo};

  #pragma unroll
  for (int p = 0; p < 3; ++p) {
    // stage 1: t1[a][y][z] = sum_x w0[a][x] * X[x][y][z]
    float4 r = make_float4(0.f, 0.f, 0.f, 0.f);
    #pragma unroll
    for (int xx = 0; xx < 8; ++xx) {
      const float w = sw0[p][a * 8 + xx];
      const float4 v = *(float4*)&sx[xx * 128 + c * 16 + dq * 4];
      fma4(r, w, v);
    }
    *(float4*)&t1[(a * 8 + c) * LDT + dq * 4] = r;
    __syncthreads();
    // stage 2: t2[a][c][z] = sum_y w1[c][y] * t1[a][y][z]
    r = make_float4(0.f, 0.f, 0.f, 0.f);
    #pragma unroll
    for (int yy = 0; yy < 8; ++yy) {
      const float w = sw1[p][c * 8 + yy];
      const float4 v = *(float4*)&t1[(a * 8 + yy) * LDT + dq * 4];
      fma4(r, w, v);
    }
    *(float4*)&t2[(a * 8 + c) * LDT + dq * 4] = r;
    __syncthreads();
    // stage 3: out[a][c][d] = sum_z w2[d][z] * t2[a][c][z] + bias
    const float* t2r = &t2[(a * 8 + c) * LDT];
    const float4 u0 = *(float4*)&t2r[0],  u1 = *(float4*)&t2r[4];
    const float4 u2 = *(float4*)&t2r[8],  u3 = *(float4*)&t2r[12];
    const float4 bias4 = *(const float4*)&biases[p][(a * 8 + c) * 16 + dq * 4];
    float o[4];
    #pragma unroll
    for (int i = 0; i < 4; ++i) {
      const float* w2r = &sw2[p][(dq * 4 + i) * 16];
      float acc = 0.f;
      acc = fmaf(w2r[0],  u0.x, acc); acc = fmaf(w2r[1],  u0.y, acc);
      acc = fmaf(w2r[2],  u0.z, acc); acc = fmaf(w2r[3],  u0.w, acc);
      acc = fmaf(w2r[4],  u1.x, acc); acc = fmaf(w2r[5],  u1.y, acc);
      acc = fmaf(w2r[6],  u1.z, acc); acc = fmaf(w2r[7],  u1.w, acc);
      acc = fmaf(w2r[8],  u2.x, acc); acc = fmaf(w2r[9],  u2.y, acc);
      acc = fmaf(w2r[10], u2.z, acc); acc = fmaf(w2r[11], u2.w, acc);
      acc = fmaf(w2r[12], u3.x, acc); acc = fmaf(w2r[13], u3.y, acc);
      acc = fmaf(w2r[14], u3.z, acc); acc = fmaf(w2r[15], u3.w, acc);
      o[i] = acc;
    }
    o[0] += bias4.x; o[1] += bias4.y; o[2] += bias4.z; o[3] += bias4.w;
    // stash merged-layout result in t1 (free after stage 2), then scatter
    *(float4*)&t1[(a * 8 + c) * LDT + dq * 4] = make_float4(o[0], o[1], o[2], o[3]);
    __syncthreads();
    float4 w4;
    w4.x = t1[sb + 0]; w4.y = t1[sb + 4]; w4.z = t1[sb + 8]; w4.w = t1[sb + 12];
    *(float4*)&outs[p][ooff] = w4;
    __syncthreads();
  }
}

// ---------------------------------------------------------------------------
// Kernel B: flash attention. Block = (q-tile 64, head, batch), 256 threads as
// (tr,tc) 16x16. Thread owns q rows {tr+16i}, score cols {tc+16j}, O cols
// {tc*4..+3}. Strided ownership keeps LDS row starts spread across banks.
// ---------------------------------------------------------------------------
__global__ __launch_bounds__(256) void attn_kernel(
    const float* __restrict__ Qg, const float* __restrict__ Kg,
    const float* __restrict__ Vg, float* __restrict__ Og)
{
  __shared__ __align__(16) float Qs[64 * LDK];
  __shared__ __align__(16) float Ks[64 * LDK];
  __shared__ __align__(16) float Vs[64 * LDK];
  __shared__ float Ps[64 * LDP];

  const int tid = threadIdx.x;
  const int qt = blockIdx.x, h = blockIdx.y, b = blockIdx.z;
  const size_t base = (size_t)(b * NH + h) * S * HD;
  const float* Qp = Qg + base;
  const float* Kp = Kg + base;
  const float* Vp = Vg + base;

  const int tr = tid >> 4, tc = tid & 15;
  const int qbase = qt * 64;
  const int dld = tc * 4;

  #pragma unroll
  for (int rep = 0; rep < 4; ++rep) {
    const int qr = rep * 16 + tr;
    const int gq = qbase + qr;
    float4 v = make_float4(0.f, 0.f, 0.f, 0.f);
    if (gq < S) v = *(const float4*)&Qp[gq * HD + dld];
    *(float4*)&Qs[qr * LDK + dld] = v;
  }

  float4 acc0 = make_float4(0.f, 0.f, 0.f, 0.f);
  float4 acc1 = acc0, acc2 = acc0, acc3 = acc0;
  float m[4] = {-1e30f, -1e30f, -1e30f, -1e30f};
  float l[4] = {0.f, 0.f, 0.f, 0.f};

  for (int kt = 0; kt < 10; ++kt) {
    const int kbase = kt * 64;
    const int kvalid = (S - kbase > 64) ? 64 : (S - kbase);
    __syncthreads();  // prev-iter PV readers of Vs/Ps done; Q load visible (iter 0)
    #pragma unroll
    for (int rep = 0; rep < 4; ++rep) {
      const int kr = rep * 16 + tr;
      const int gk = kbase + kr;
      float4 kv = make_float4(0.f, 0.f, 0.f, 0.f), vv = kv;
      if (gk < S) {
        kv = *(const float4*)&Kp[gk * HD + dld];
        vv = *(const float4*)&Vp[gk * HD + dld];
      }
      *(float4*)&Ks[kr * LDK + dld] = kv;
      *(float4*)&Vs[kr * LDK + dld] = vv;
    }
    __syncthreads();

    // QK^T: s[i][j] = Q[tr+16i] . K[tc+16j]
    float s[4][4] = {{0.f,0.f,0.f,0.f},{0.f,0.f,0.f,0.f},
                     {0.f,0.f,0.f,0.f},{0.f,0.f,0.f,0.f}};
    #pragma unroll 4
    for (int d = 0; d < HD; d += 4) {
      const float4 q0 = *(float4*)&Qs[(tr     ) * LDK + d];
      const float4 q1 = *(float4*)&Qs[(tr + 16) * LDK + d];
      const float4 q2 = *(float4*)&Qs[(tr + 32) * LDK + d];
      const float4 q3 = *(float4*)&Qs[(tr + 48) * LDK + d];
      const float4 k0 = *(float4*)&Ks[(tc     ) * LDK + d];
      const float4 k1 = *(float4*)&Ks[(tc + 16) * LDK + d];
      const float4 k2 = *(float4*)&Ks[(tc + 32) * LDK + d];
      const float4 k3 = *(float4*)&Ks[(tc + 48) * LDK + d];
      dot4(s[0][0], q0, k0); dot4(s[0][1], q0, k1); dot4(s[0][2], q0, k2); dot4(s[0][3], q0, k3);
      dot4(s[1][0], q1, k0); dot4(s[1][1], q1, k1); dot4(s[1][2], q1, k2); dot4(s[1][3], q1, k3);
      dot4(s[2][0], q2, k0); dot4(s[2][1], q2, k1); dot4(s[2][2], q2, k2); dot4(s[2][3], q2, k3);
      dot4(s[3][0], q3, k0); dot4(s[3][1], q3, k1); dot4(s[3][2], q3, k2); dot4(s[3][3], q3, k3);
    }

    // online softmax update (rows owned per-thread; reduce across 16 tc lanes)
    #pragma unroll
    for (int i = 0; i < 4; ++i) {
      #pragma unroll
      for (int j = 0; j < 4; ++j)
        s[i][j] = (tc + 16 * j < kvalid) ? s[i][j] * SCALE : -1e30f;
      float tm = fmaxf(fmaxf(s[i][0], s[i][1]), fmaxf(s[i][2], s[i][3]));
      tm = fmaxf(tm, __shfl_xor(tm, 1));
      tm = fmaxf(tm, __shfl_xor(tm, 2));
      tm = fmaxf(tm, __shfl_xor(tm, 4));
      tm = fmaxf(tm, __shfl_xor(tm, 8));
      const float mn = fmaxf(m[i], tm);
      const float corr = __expf(m[i] - mn);
      float rs = 0.f;
      #pragma unroll
      for (int j = 0; j < 4; ++j) { s[i][j] = __expf(s[i][j] - mn); rs += s[i][j]; }
      rs += __shfl_xor(rs, 1);
      rs += __shfl_xor(rs, 2);
      rs += __shfl_xor(rs, 4);
      rs += __shfl_xor(rs, 8);
      l[i] = l[i] * corr + rs;
      m[i] = mn;
      float4* ar = (i == 0) ? &acc0 : (i == 1) ? &acc1 : (i == 2) ? &acc2 : &acc3;
      ar->x *= corr; ar->y *= corr; ar->z *= corr; ar->w *= corr;
      Ps[(tr + 16 * i) * LDP + tc     ] = s[i][0];
      Ps[(tr + 16 * i) * LDP + tc + 16] = s[i][1];
      Ps[(tr + 16 * i) * LDP + tc + 32] = s[i][2];
      Ps[(tr + 16 * i) * LDP + tc + 48] = s[i][3];
    }
    __syncthreads();

    // PV: O[q][tc*4..] += sum_k P[q][k] * V[k][tc*4..]
    #pragma unroll 4
    for (int kk = 0; kk < kvalid; ++kk) {
      const float4 vv = *(float4*)&Vs[kk * LDK + tc * 4];
      const float p0 = Ps[(tr     ) * LDP + kk];
      const float p1 = Ps[(tr + 16) * LDP + kk];
      const float p2 = Ps[(tr + 32) * LDP + kk];
      const float p3 = Ps[(tr + 48) * LDP + kk];
      fma4(acc0, p0, vv); fma4(acc1, p1, vv);
      fma4(acc2, p2, vv); fma4(acc3, p3, vv);
    }
  }

  #pragma unroll
  for (int i = 0; i < 4; ++i) {
    const int gq = qbase + tr + 16 * i;
    if (gq < S) {
      const float inv = 1.0f / l[i];
      const float4 a = (i == 0) ? acc0 : (i == 1) ? acc1 : (i == 2) ? acc2 : acc3;
      *(float4*)&Og[base + (size_t)gq * HD + tc * 4] =
          make_float4(a.x * inv, a.y * inv, a.z * inv, a.w * inv);
    }
  }
}

// ---------------------------------------------------------------------------
// Kernel C: gather heads -> merged embed, then TCL with o weights -> d_out.
// ---------------------------------------------------------------------------
__global__ __launch_bounds__(256) void tcl_out_kernel(
    const float* __restrict__ Og,
    const float* __restrict__ ow0, const float* __restrict__ ow1,
    const float* __restrict__ ow2, const float* __restrict__ ob,
    float* __restrict__ out)
{
  __shared__ __align__(16) float sx[1024];
  __shared__ __align__(16) float t1[64 * LDT];
  __shared__ __align__(16) float t2[64 * LDT];
  __shared__ float sw0[64], sw1[64], sw2[256];

  const int tid = threadIdx.x;
  const int t = blockIdx.x, b = blockIdx.y;

  {
    const int h = tid >> 4, dimq = tid & 15;
    const int xs = dimq >> 2, ys = dimq & 3;
    const int aa = 2 * xs + (h >> 3), cc = 2 * ys + ((h >> 2) & 1), h3 = h & 3;
    const float4 v = *(const float4*)&Og[((size_t)(b * NH + h) * S + t) * HD + dimq * 4];
    float* sr = &sx[(aa * 8 + cc) * 16 + h3];
    sr[0] = v.x; sr[4] = v.y; sr[8] = v.z; sr[12] = v.w;
  }
  if (tid < 64) { sw0[tid] = ow0[tid]; sw1[tid] = ow1[tid]; }
  sw2[tid] = ow2[tid];
  __syncthreads();

  const int a = tid >> 5, c = (tid >> 2) & 7, dq = tid & 3;

  float4 r = make_float4(0.f, 0.f, 0.f, 0.f);
  #pragma unroll
  for (int xx = 0; xx < 8; ++xx) {
    const float w = sw0[a * 8 + xx];
    const float4 v = *(float4*)&sx[xx * 128 + c * 16 + dq * 4];
    fma4(r, w, v);
  }
  *(float4*)&t1[(a * 8 + c) * LDT + dq * 4] = r;
  __syncthreads();
  r = make_float4(0.f, 0.f, 0.f, 0.f);
  #pragma unroll
  for (int yy = 0; yy < 8; ++yy) {
    const float w = sw1[c * 8 + yy];
    const float4 v = *(float4*)&t1[(a * 8 + yy) * LDT + dq * 4];
    fma4(r, w, v);
  }
  *(float4*)&t2[(a * 8 + c) * LDT + dq * 4] = r;
  __syncthreads();
  const float* t2r = &t2[(a * 8 + c) * LDT];
  const float4 u0 = *(float4*)&t2r[0],  u1 = *(float4*)&t2r[4];
  const float4 u2 = *(float4*)&t2r[8],  u3 = *(float4*)&t2r[12];
  const float4 bias4 = *(const float4*)&ob[(a * 8 + c) * 16 + dq * 4];
  float o[4];
  #pragma unroll
  for (int i = 0; i < 4; ++i) {
    const float* w2r = &sw2[(dq * 4 + i) * 16];
    float acc = 0.f;
    acc = fmaf(w2r[0],  u0.x, acc); acc = fmaf(w2r[1],  u0.y, acc);
    acc = fmaf(w2r[2],  u0.z, acc); acc = fmaf(w2r[3],  u0.w, acc);
    acc = fmaf(w2r[4],  u1.x, acc); acc = fmaf(w2r[5],  u1.y, acc);
    acc = fmaf(w2r[6],  u1.z, acc); acc = fmaf(w2r[7],  u1.w, acc);
    acc = fmaf(w2r[8],  u2.x, acc); acc = fmaf(w2r[9],  u2.y, acc);
    acc = fmaf(w2r[10], u2.z, acc); acc = fmaf(w2r[11], u2.w, acc);
    acc = fmaf(w2r[12], u3.x, acc); acc = fmaf(w2r[13], u3.y, acc);
    acc = fmaf(w2r[14], u3.z, acc); acc = fmaf(w2r[15], u3.w, acc);
    o[i] = acc;
  }
  const float4 res = make_float4(o[0] + bias4.x, o[1] + bias4.y,
                                 o[2] + bias4.z, o[3] + bias4.w);
  *(float4*)&out[((size_t)(b * S + t)) * 1024 + (a * 8 + c) * 16 + dq * 4] = res;
}

// ---------------------------------------------------------------------------
extern "C" void kernel_launch(void* const* d_in, const int* in_sizes, int n_in,
                              void* d_out, int out_size, void* d_ws, size_t ws_size,
                              hipStream_t stream) {
  const float* x   = (const float*)d_in[0];
  const float* qw0 = (const float*)d_in[1];
  const float* qw1 = (const float*)d_in[2];
  const float* qw2 = (const float*)d_in[3];
  const float* qb  = (const float*)d_in[4];
  const float* kw0 = (const float*)d_in[5];
  const float* kw1 = (const float*)d_in[6];
  const float* kw2 = (const float*)d_in[7];
  const float* kb  = (const float*)d_in[8];
  const float* vw0 = (const float*)d_in[9];
  const float* vw1 = (const float*)d_in[10];
  const float* vw2 = (const float*)d_in[11];
  const float* vb  = (const float*)d_in[12];
  const float* ow0 = (const float*)d_in[13];
  const float* ow1 = (const float*)d_in[14];
  const float* ow2 = (const float*)d_in[15];
  const float* ob  = (const float*)d_in[16];

  const size_t N = (size_t)NB * NH * S * HD;  // 9,830,400 floats per buffer
  float* ws = (float*)d_ws;
  float* Q = ws;
  float* K = ws + N;
  float* V = ws + 2 * N;
  // O aliases Q if workspace is tight: safe — each Q row is read into LDS by
  // exactly one block, fully before that block's O writes (separated by many
  // __syncthreads), and blocks touch disjoint (b,h,q) row sets.
  float* O = (ws_size >= 4 * N * sizeof(float)) ? (ws + 3 * N) : Q;

  tcl_qkv_kernel<<<dim3(S, NB), 256, 0, stream>>>(
      x, qw0, qw1, qw2, qb, kw0, kw1, kw2, kb, vw0, vw1, vw2, vb, Q, K, V);
  attn_kernel<<<dim3(10, NH, NB), 256, 0, stream>>>(Q, K, V, O);
  tcl_out_kernel<<<dim3(S, NB), 256, 0, stream>>>(O, ow0, ow1, ow2, ob,
                                                  (float*)d_out);
}

// Round 4
// 212.127 us; speedup vs baseline: 2.7243x; 2.7243x over previous
//
#include <hip/hip_runtime.h>

// Problem constants:
//   B=16, P1=25, P2=24 -> S=600 tokens; E=(8,8,16)=1024; heads (2,2,4)=16, head_dim 64
#define S   600
#define NB  16
#define NH  16
#define HD  64
#define SCALE 0.125f   // (4*4*4)^-0.5, folded into Q at f16-cast time

#define LDT 20   // TCL intermediate row stride

typedef _Float16 f16x8 __attribute__((ext_vector_type(8)));
typedef float f32x4 __attribute__((ext_vector_type(4)));

__device__ __forceinline__ void fma4(float4& a, const float p, const float4 v) {
  a.x = fmaf(p, v.x, a.x); a.y = fmaf(p, v.y, a.y);
  a.z = fmaf(p, v.z, a.z); a.w = fmaf(p, v.w, a.w);
}

// ---------------------------------------------------------------------------
// Kernel A: TCL for q,k,v (fp32 compute). Emits f16:
//   Qh [b,h,s,64]  (values pre-scaled by SCALE)
//   Kh [b,h,s,64]
//   Vt [b,h,64,600]  (transposed: dim-major, so attention's V^T loads are rows)
// ---------------------------------------------------------------------------
__global__ __launch_bounds__(256) void tcl_qkv_kernel(
    const float* __restrict__ x,
    const float* __restrict__ qw0, const float* __restrict__ qw1,
    const float* __restrict__ qw2, const float* __restrict__ qb,
    const float* __restrict__ kw0, const float* __restrict__ kw1,
    const float* __restrict__ kw2, const float* __restrict__ kb,
    const float* __restrict__ vw0, const float* __restrict__ vw1,
    const float* __restrict__ vw2, const float* __restrict__ vb,
    _Float16* __restrict__ Qh, _Float16* __restrict__ Kh,
    _Float16* __restrict__ Vth)
{
  __shared__ __align__(16) float sx[1024];       // [x][y][z] natural
  __shared__ __align__(16) float t1[64 * LDT];
  __shared__ __align__(16) float t2[64 * LDT];
  __shared__ float sw0[3][64], sw1[3][64], sw2[3][256];

  const int tid = threadIdx.x;
  const int t = blockIdx.x, b = blockIdx.y;
  const size_t tok = (size_t)b * S + t;

  *(float4*)&sx[tid * 4] = *(const float4*)&x[tok * 1024 + tid * 4];
  if (tid < 64) {
    sw0[0][tid] = qw0[tid]; sw0[1][tid] = kw0[tid]; sw0[2][tid] = vw0[tid];
    sw1[0][tid] = qw1[tid]; sw1[1][tid] = kw1[tid]; sw1[2][tid] = vw1[tid];
  }
  sw2[0][tid] = qw2[tid]; sw2[1][tid] = kw2[tid]; sw2[2][tid] = vw2[tid];
  __syncthreads();

  const int a = tid >> 5, c = (tid >> 2) & 7, dq = tid & 3;
  // scatter mapping: thread -> (head, dim-quad)
  const int h = tid >> 4, dimq = tid & 15;
  const int xs = dimq >> 2, ys = dimq & 3;
  const int aa = 2 * xs + (h >> 3), cc = 2 * ys + ((h >> 2) & 1), h3 = h & 3;
  const int sb = (aa * 8 + cc) * LDT + h3;
  const size_t ooff = ((size_t)(b * NH + h) * S + t) * HD + dimq * 4;  // Q/K half idx
  const size_t vtb = ((size_t)(b * NH + h) * HD + dimq * 4) * S + t;   // Vt half idx

  const float* biases[3] = {qb, kb, vb};

  #pragma unroll
  for (int p = 0; p < 3; ++p) {
    float4 r = make_float4(0.f, 0.f, 0.f, 0.f);
    #pragma unroll
    for (int xx = 0; xx < 8; ++xx) {
      const float w = sw0[p][a * 8 + xx];
      const float4 v = *(float4*)&sx[xx * 128 + c * 16 + dq * 4];
      fma4(r, w, v);
    }
    *(float4*)&t1[(a * 8 + c) * LDT + dq * 4] = r;
    __syncthreads();
    r = make_float4(0.f, 0.f, 0.f, 0.f);
    #pragma unroll
    for (int yy = 0; yy < 8; ++yy) {
      const float w = sw1[p][c * 8 + yy];
      const float4 v = *(float4*)&t1[(a * 8 + yy) * LDT + dq * 4];
      fma4(r, w, v);
    }
    *(float4*)&t2[(a * 8 + c) * LDT + dq * 4] = r;
    __syncthreads();
    const float* t2r = &t2[(a * 8 + c) * LDT];
    const float4 u0 = *(float4*)&t2r[0],  u1 = *(float4*)&t2r[4];
    const float4 u2 = *(float4*)&t2r[8],  u3 = *(float4*)&t2r[12];
    const float4 bias4 = *(const float4*)&biases[p][(a * 8 + c) * 16 + dq * 4];
    float o[4];
    #pragma unroll
    for (int i = 0; i < 4; ++i) {
      const float* w2r = &sw2[p][(dq * 4 + i) * 16];
      float acc = 0.f;
      acc = fmaf(w2r[0],  u0.x, acc); acc = fmaf(w2r[1],  u0.y, acc);
      acc = fmaf(w2r[2],  u0.z, acc); acc = fmaf(w2r[3],  u0.w, acc);
      acc = fmaf(w2r[4],  u1.x, acc); acc = fmaf(w2r[5],  u1.y, acc);
      acc = fmaf(w2r[6],  u1.z, acc); acc = fmaf(w2r[7],  u1.w, acc);
      acc = fmaf(w2r[8],  u2.x, acc); acc = fmaf(w2r[9],  u2.y, acc);
      acc = fmaf(w2r[10], u2.z, acc); acc = fmaf(w2r[11], u2.w, acc);
      acc = fmaf(w2r[12], u3.x, acc); acc = fmaf(w2r[13], u3.y, acc);
      acc = fmaf(w2r[14], u3.z, acc); acc = fmaf(w2r[15], u3.w, acc);
      o[i] = acc;
    }
    o[0] += bias4.x; o[1] += bias4.y; o[2] += bias4.z; o[3] += bias4.w;
    *(float4*)&t1[(a * 8 + c) * LDT + dq * 4] = make_float4(o[0], o[1], o[2], o[3]);
    __syncthreads();
    float4 w4;
    w4.x = t1[sb + 0]; w4.y = t1[sb + 4]; w4.z = t1[sb + 8]; w4.w = t1[sb + 12];
    if (p == 0) {
      union { _Float16 hh[4]; uint2 u; } pk;
      pk.hh[0] = (_Float16)(w4.x * SCALE); pk.hh[1] = (_Float16)(w4.y * SCALE);
      pk.hh[2] = (_Float16)(w4.z * SCALE); pk.hh[3] = (_Float16)(w4.w * SCALE);
      *(uint2*)&Qh[ooff] = pk.u;
    } else if (p == 1) {
      union { _Float16 hh[4]; uint2 u; } pk;
      pk.hh[0] = (_Float16)w4.x; pk.hh[1] = (_Float16)w4.y;
      pk.hh[2] = (_Float16)w4.z; pk.hh[3] = (_Float16)w4.w;
      *(uint2*)&Kh[ooff] = pk.u;
    } else {
      Vth[vtb        ] = (_Float16)w4.x;
      Vth[vtb +     S] = (_Float16)w4.y;
      Vth[vtb + 2 * S] = (_Float16)w4.z;
      Vth[vtb + 3 * S] = (_Float16)w4.w;
    }
    __syncthreads();
  }
}

// ---------------------------------------------------------------------------
// Kernel B: MFMA flash attention. Block = 256 thr (4 waves), one 64-q-row tile
// of one (b,h). Wave w owns q-rows [qt*64+w*16, +16).
//   S^T = K * Q^T  (mfma A=K-rows, B=Q-rows; C col = q-row = lane&15)
//   softmax per q-row: lane-local over 16 keys + shfl_xor(16,32)
//   O^T = V^T * P^T (mfma A=Vt-rows, B=P rows read from swizzled LDS)
// K/Vt/P LDS tiles XOR-swizzled: 16B-chunk index ^= (row&7)  -> conflict-free.
// Wave-internal LDS exchanges (P relay, epilogue transpose) are fenced with
// __builtin_amdgcn_wave_barrier(): zero-instruction compiler fence; HW DS ops
// within a wave complete in issue order, so no __syncthreads needed.
// ---------------------------------------------------------------------------
__global__ __launch_bounds__(256) void attn_mfma_kernel(
    const _Float16* __restrict__ Qh, const _Float16* __restrict__ Kh,
    const _Float16* __restrict__ Vt, float* __restrict__ Og)
{
  __shared__ __align__(16) union {
    struct {
      _Float16 K[64 * 64];      // swizzled [key][d]
      _Float16 V[64 * 64];      // swizzled [d][key] (tile of Vt)
      _Float16 P[4][16 * 64];   // per-wave swizzled [qrow][key]
    } m;
    float ot[4][64 * 17];       // epilogue per-wave O^T staging (17408B < 24576B)
  } sm;

  const int tid = threadIdx.x;
  const int lane = tid & 63;
  const int wv = tid >> 6;
  const int qt = blockIdx.x, h = blockIdx.y, b = blockIdx.z;
  const size_t base  = (size_t)(b * NH + h) * S * HD;   // Q,K,O
  const size_t vbase = (size_t)(b * NH + h) * HD * S;   // Vt
  const int lr = lane & 15;   // row/col-in-16
  const int lg = lane >> 4;   // k-group

  // Q B-fragments, held in registers for all 10 key tiles
  const int qrow_l = qt * 64 + wv * 16 + lr;
  const int qrow = (qrow_l < S) ? qrow_l : (S - 1);
  f16x8 qf0 = *(const f16x8*)&Qh[base + (size_t)qrow * HD + lg * 8];
  f16x8 qf1 = *(const f16x8*)&Qh[base + (size_t)qrow * HD + 32 + lg * 8];

  f32x4 po[4] = {{0.f,0.f,0.f,0.f},{0.f,0.f,0.f,0.f},
                 {0.f,0.f,0.f,0.f},{0.f,0.f,0.f,0.f}};
  float mrow = -1e30f, lrow = 0.f;

  for (int kt = 0; kt < 10; ++kt) {
    const int kb = kt * 64;
    __syncthreads();   // previous tile fully consumed
    #pragma unroll
    for (int hp = 0; hp < 2; ++hp) {
      const int u = hp * 256 + tid;
      const int row = u >> 3, ch = u & 7;
      const int swz = ((ch ^ (row & 7)) * 8);
      f16x8 kv = {0,0,0,0,0,0,0,0};
      if (kb + row < S)
        kv = *(const f16x8*)&Kh[base + (size_t)(kb + row) * HD + ch * 8];
      *(f16x8*)&sm.m.K[row * 64 + swz] = kv;
      f16x8 vv = {0,0,0,0,0,0,0,0};
      if (kb + ch * 8 + 8 <= S)   // 600 % 8 == 0: full-or-none chunks
        vv = *(const f16x8*)&Vt[vbase + (size_t)row * S + kb + ch * 8];
      *(f16x8*)&sm.m.V[row * 64 + swz] = vv;
    }
    __syncthreads();

    // --- S^T: keys (rows) x 16 q-cols, K-dim = 64 (2 chunks) ---
    f32x4 accs[4] = {{0.f,0.f,0.f,0.f},{0.f,0.f,0.f,0.f},
                     {0.f,0.f,0.f,0.f},{0.f,0.f,0.f,0.f}};
    #pragma unroll
    for (int c = 0; c < 2; ++c) {
      const f16x8 qf = c ? qf1 : qf0;
      #pragma unroll
      for (int mt = 0; mt < 4; ++mt) {
        const int krow = mt * 16 + lr;
        const f16x8 kf = *(const f16x8*)
            &sm.m.K[krow * 64 + (((4 * c + lg) ^ (krow & 7)) * 8)];
        accs[mt] = __builtin_amdgcn_mfma_f32_16x16x32_f16(kf, qf, accs[mt], 0, 0, 0);
      }
    }

    // --- online softmax (lane owns q-row lr; holds keys mt*16+4*lg+r) ---
    float sv[4][4];
    float tmax = -1e30f;
    #pragma unroll
    for (int mt = 0; mt < 4; ++mt)
      #pragma unroll
      for (int r = 0; r < 4; ++r) {
        float s = accs[mt][r];
        if (kb + mt * 16 + 4 * lg + r >= S) s = -1e30f;
        sv[mt][r] = s;
        tmax = fmaxf(tmax, s);
      }
    tmax = fmaxf(tmax, __shfl_xor(tmax, 16));
    tmax = fmaxf(tmax, __shfl_xor(tmax, 32));
    const float mn = fmaxf(mrow, tmax);
    const float corr = __expf(mrow - mn);
    float rs = 0.f;
    _Float16 ph[4][4];
    #pragma unroll
    for (int mt = 0; mt < 4; ++mt)
      #pragma unroll
      for (int r = 0; r < 4; ++r) {
        const float pv = __expf(sv[mt][r] - mn);
        rs += pv;
        ph[mt][r] = (_Float16)pv;
      }
    rs += __shfl_xor(rs, 16);
    rs += __shfl_xor(rs, 32);
    lrow = lrow * corr + rs;
    mrow = mn;
    #pragma unroll
    for (int dt = 0; dt < 4; ++dt) {
      po[dt][0] *= corr; po[dt][1] *= corr;
      po[dt][2] *= corr; po[dt][3] *= corr;
    }

    // --- P -> per-wave swizzled LDS (keys mt*16+4*lg+0..3 at row lr) ---
    #pragma unroll
    for (int mt = 0; mt < 4; ++mt) {
      union { _Float16 hh[4]; unsigned long long u; } pk;
      pk.hh[0] = ph[mt][0]; pk.hh[1] = ph[mt][1];
      pk.hh[2] = ph[mt][2]; pk.hh[3] = ph[mt][3];
      const int idx = lr * 64 + (((2 * mt + (lg >> 1)) ^ (lr & 7)) * 8)
                    + (lg & 1) * 4;
      *(unsigned long long*)&sm.m.P[wv][idx] = pk.u;
    }
    __builtin_amdgcn_wave_barrier();   // fence: P writes before P reads (same wave)

    // --- O^T += V^T * P^T ---
    #pragma unroll
    for (int c = 0; c < 2; ++c) {
      const f16x8 pf = *(const f16x8*)
          &sm.m.P[wv][lr * 64 + (((4 * c + lg) ^ (lr & 7)) * 8)];
      #pragma unroll
      for (int dt = 0; dt < 4; ++dt) {
        const int drow = dt * 16 + lr;
        const f16x8 vf = *(const f16x8*)
            &sm.m.V[drow * 64 + (((4 * c + lg) ^ (drow & 7)) * 8)];
        po[dt] = __builtin_amdgcn_mfma_f32_16x16x32_f16(vf, pf, po[dt], 0, 0, 0);
      }
    }
  }

  __syncthreads();   // main-loop LDS fully consumed before epilogue reuse

  // epilogue: O^T -> per-wave LDS -> transposed, coalesced f32 global write
  const float invl = 1.0f / lrow;
  #pragma unroll
  for (int dt = 0; dt < 4; ++dt)
    #pragma unroll
    for (int r = 0; r < 4; ++r)
      sm.ot[wv][(dt * 16 + 4 * lg + r) * 17 + lr] = po[dt][r] * invl;
  __builtin_amdgcn_wave_barrier();   // fence: ot writes before ot reads (same wave)
  #pragma unroll
  for (int ps = 0; ps < 4; ++ps) {
    const int qr = ps * 4 + lg;
    const int gq = qt * 64 + wv * 16 + qr;
    if (gq < S) {
      const int d0 = lr * 4;
      float4 o4;
      o4.x = sm.ot[wv][(d0 + 0) * 17 + qr];
      o4.y = sm.ot[wv][(d0 + 1) * 17 + qr];
      o4.z = sm.ot[wv][(d0 + 2) * 17 + qr];
      o4.w = sm.ot[wv][(d0 + 3) * 17 + qr];
      *(float4*)&Og[base + (size_t)gq * HD + d0] = o4;
    }
  }
}

// ---------------------------------------------------------------------------
// Kernel C: gather heads -> merged embed, then TCL with o weights -> d_out.
// ---------------------------------------------------------------------------
__global__ __launch_bounds__(256) void tcl_out_kernel(
    const float* __restrict__ Og,
    const float* __restrict__ ow0, const float* __restrict__ ow1,
    const float* __restrict__ ow2, const float* __restrict__ ob,
    float* __restrict__ out)
{
  __shared__ __align__(16) float sx[1024];
  __shared__ __align__(16) float t1[64 * LDT];
  __shared__ __align__(16) float t2[64 * LDT];
  __shared__ float sw0[64], sw1[64], sw2[256];

  const int tid = threadIdx.x;
  const int t = blockIdx.x, b = blockIdx.y;

  {
    const int h = tid >> 4, dimq = tid & 15;
    const int xs = dimq >> 2, ys = dimq & 3;
    const int aa = 2 * xs + (h >> 3), cc = 2 * ys + ((h >> 2) & 1), h3 = h & 3;
    const float4 v = *(const float4*)&Og[((size_t)(b * NH + h) * S + t) * HD + dimq * 4];
    float* sr = &sx[(aa * 8 + cc) * 16 + h3];
    sr[0] = v.x; sr[4] = v.y; sr[8] = v.z; sr[12] = v.w;
  }
  if (tid < 64) { sw0[tid] = ow0[tid]; sw1[tid] = ow1[tid]; }
  sw2[tid] = ow2[tid];
  __syncthreads();

  const int a = tid >> 5, c = (tid >> 2) & 7, dq = tid & 3;

  float4 r = make_float4(0.f, 0.f, 0.f, 0.f);
  #pragma unroll
  for (int xx = 0; xx < 8; ++xx) {
    const float w = sw0[a * 8 + xx];
    const float4 v = *(float4*)&sx[xx * 128 + c * 16 + dq * 4];
    fma4(r, w, v);
  }
  *(float4*)&t1[(a * 8 + c) * LDT + dq * 4] = r;
  __syncthreads();
  r = make_float4(0.f, 0.f, 0.f, 0.f);
  #pragma unroll
  for (int yy = 0; yy < 8; ++yy) {
    const float w = sw1[c * 8 + yy];
    const float4 v = *(float4*)&t1[(a * 8 + yy) * LDT + dq * 4];
    fma4(r, w, v);
  }
  *(float4*)&t2[(a * 8 + c) * LDT + dq * 4] = r;
  __syncthreads();
  const float* t2r = &t2[(a * 8 + c) * LDT];
  const float4 u0 = *(float4*)&t2r[0],  u1 = *(float4*)&t2r[4];
  const float4 u2 = *(float4*)&t2r[8],  u3 = *(float4*)&t2r[12];
  const float4 bias4 = *(const float4*)&ob[(a * 8 + c) * 16 + dq * 4];
  float o[4];
  #pragma unroll
  for (int i = 0; i < 4; ++i) {
    const float* w2r = &sw2[(dq * 4 + i) * 16];
    float acc = 0.f;
    acc = fmaf(w2r[0],  u0.x, acc); acc = fmaf(w2r[1],  u0.y, acc);
    acc = fmaf(w2r[2],  u0.z, acc); acc = fmaf(w2r[3],  u0.w, acc);
    acc = fmaf(w2r[4],  u1.x, acc); acc = fmaf(w2r[5],  u1.y, acc);
    acc = fmaf(w2r[6],  u1.z, acc); acc = fmaf(w2r[7],  u1.w, acc);
    acc = fmaf(w2r[8],  u2.x, acc); acc = fmaf(w2r[9],  u2.y, acc);
    acc = fmaf(w2r[10], u2.z, acc); acc = fmaf(w2r[11], u2.w, acc);
    acc = fmaf(w2r[12], u3.x, acc); acc = fmaf(w2r[13], u3.y, acc);
    acc = fmaf(w2r[14], u3.z, acc); acc = fmaf(w2r[15], u3.w, acc);
    o[i] = acc;
  }
  const float4 res = make_float4(o[0] + bias4.x, o[1] + bias4.y,
                                 o[2] + bias4.z, o[3] + bias4.w);
  *(float4*)&out[((size_t)(b * S + t)) * 1024 + (a * 8 + c) * 16 + dq * 4] = res;
}

// ---------------------------------------------------------------------------
extern "C" void kernel_launch(void* const* d_in, const int* in_sizes, int n_in,
                              void* d_out, int out_size, void* d_ws, size_t ws_size,
                              hipStream_t stream) {
  const float* x   = (const float*)d_in[0];
  const float* qw0 = (const float*)d_in[1];
  const float* qw1 = (const float*)d_in[2];
  const float* qw2 = (const float*)d_in[3];
  const float* qb  = (const float*)d_in[4];
  const float* kw0 = (const float*)d_in[5];
  const float* kw1 = (const float*)d_in[6];
  const float* kw2 = (const float*)d_in[7];
  const float* kb  = (const float*)d_in[8];
  const float* vw0 = (const float*)d_in[9];
  const float* vw1 = (const float*)d_in[10];
  const float* vw2 = (const float*)d_in[11];
  const float* vb  = (const float*)d_in[12];
  const float* ow0 = (const float*)d_in[13];
  const float* ow1 = (const float*)d_in[14];
  const float* ow2 = (const float*)d_in[15];
  const float* ob  = (const float*)d_in[16];

  const size_t N = (size_t)NB * NH * S * HD;  // 9,830,400 elems per logical buffer
  _Float16* Qh  = (_Float16*)d_ws;
  _Float16* Kh  = Qh + N;
  _Float16* Vth = Kh + N;
  float*    O   = (float*)(Vth + N);   // 3*N*2 B offset = 58,982,400 (16B-aligned)
  // total ws use: 3*N*2 + N*4 = 98.3 MB (< the >=118 MB R1 demonstrated)

  tcl_qkv_kernel<<<dim3(S, NB), 256, 0, stream>>>(
      x, qw0, qw1, qw2, qb, kw0, kw1, kw2, kb, vw0, vw1, vw2, vb, Qh, Kh, Vth);
  attn_mfma_kernel<<<dim3(10, NH, NB), 256, 0, stream>>>(Qh, Kh, Vth, O);
  tcl_out_kernel<<<dim3(S, NB), 256, 0, stream>>>(O, ow0, ow1, ow2, ob,
                                                  (float*)d_out);
}

// Round 5
// 192.624 us; speedup vs baseline: 3.0002x; 1.1013x over previous
//
#include <hip/hip_runtime.h>

// Problem constants:
//   B=16, P1=25, P2=24 -> S=600 tokens; E=(8,8,16)=1024; heads (2,2,4)=16, head_dim 64
#define S   600
#define NB  16
#define NH  16
#define HD  64
#define SCALE 0.125f   // (4*4*4)^-0.5, folded into Q at f16-cast time

#define LDT 20   // TCL intermediate row stride

typedef _Float16 f16x8 __attribute__((ext_vector_type(8)));
typedef float f32x4 __attribute__((ext_vector_type(4)));

__device__ __forceinline__ void fma4(float4& a, const float p, const float4 v) {
  a.x = fmaf(p, v.x, a.x); a.y = fmaf(p, v.y, a.y);
  a.z = fmaf(p, v.z, a.z); a.w = fmaf(p, v.w, a.w);
}

// ---------------------------------------------------------------------------
// Kernel A: TCL for q,k,v (fp32 compute). Emits f16, ALL row-major coalesced:
//   Qh [b,h,s,64] (pre-scaled by SCALE), Kh [b,h,s,64], Vh [b,h,s,64].
// Stage-3 threads use the (h,dimq) output mapping directly (no stash/scatter):
//   head h=(h1*2+h2)*4+h3, dim=x*16+y*4+z; merged a=2x+h1, c=2y+h2, e2=4z+h3.
// ---------------------------------------------------------------------------
__global__ __launch_bounds__(256) void tcl_qkv_kernel(
    const float* __restrict__ x,
    const float* __restrict__ qw0, const float* __restrict__ qw1,
    const float* __restrict__ qw2, const float* __restrict__ qb,
    const float* __restrict__ kw0, const float* __restrict__ kw1,
    const float* __restrict__ kw2, const float* __restrict__ kb,
    const float* __restrict__ vw0, const float* __restrict__ vw1,
    const float* __restrict__ vw2, const float* __restrict__ vb,
    _Float16* __restrict__ Qh, _Float16* __restrict__ Kh,
    _Float16* __restrict__ Vh)
{
  __shared__ __align__(16) float sx[1024];       // [x][y][z] natural
  __shared__ __align__(16) float t1[64 * LDT];
  __shared__ __align__(16) float t2[64 * LDT];
  __shared__ float sw0[3][64], sw1[3][64], sw2[3][256];

  const int tid = threadIdx.x;
  const int t = blockIdx.x, b = blockIdx.y;
  const size_t tok = (size_t)b * S + t;

  *(float4*)&sx[tid * 4] = *(const float4*)&x[tok * 1024 + tid * 4];
  if (tid < 64) {
    sw0[0][tid] = qw0[tid]; sw0[1][tid] = kw0[tid]; sw0[2][tid] = vw0[tid];
    sw1[0][tid] = qw1[tid]; sw1[1][tid] = kw1[tid]; sw1[2][tid] = vw1[tid];
  }
  sw2[0][tid] = qw2[tid]; sw2[1][tid] = kw2[tid]; sw2[2][tid] = vw2[tid];
  __syncthreads();

  // stages 1-2 mapping: thread -> (a, c, dq)
  const int a = tid >> 5, c = (tid >> 2) & 7, dq = tid & 3;
  // stage-3/output mapping: thread -> (head, dim-quad)
  const int h = tid >> 4, dimq = tid & 15;
  const int xs = dimq >> 2, ys = dimq & 3;
  const int aa = 2 * xs + (h >> 3), cc = 2 * ys + ((h >> 2) & 1), h3 = h & 3;
  const int r16 = aa * 8 + cc;
  const size_t ooff = ((size_t)(b * NH + h) * S + t) * HD + dimq * 4;

  const float* biases[3] = {qb, kb, vb};
  _Float16* outs[3] = {Qh, Kh, Vh};

  #pragma unroll
  for (int p = 0; p < 3; ++p) {
    // stage 1: t1[a][y][z] = sum_x w0[a][x] * X[x][y][z]
    float4 r = make_float4(0.f, 0.f, 0.f, 0.f);
    #pragma unroll
    for (int xx = 0; xx < 8; ++xx) {
      const float w = sw0[p][a * 8 + xx];
      const float4 v = *(float4*)&sx[xx * 128 + c * 16 + dq * 4];
      fma4(r, w, v);
    }
    *(float4*)&t1[(a * 8 + c) * LDT + dq * 4] = r;
    __syncthreads();
    // stage 2: t2[a][c][z] = sum_y w1[c][y] * t1[a][y][z]
    r = make_float4(0.f, 0.f, 0.f, 0.f);
    #pragma unroll
    for (int yy = 0; yy < 8; ++yy) {
      const float w = sw1[p][c * 8 + yy];
      const float4 v = *(float4*)&t1[(a * 8 + yy) * LDT + dq * 4];
      fma4(r, w, v);
    }
    *(float4*)&t2[(a * 8 + c) * LDT + dq * 4] = r;
    __syncthreads();
    // stage 3: thread owns output quad (merged row r16, d = h3+4i, i=0..3)
    const float* t2r = &t2[r16 * LDT];
    const float4 u0 = *(float4*)&t2r[0],  u1 = *(float4*)&t2r[4];
    const float4 u2 = *(float4*)&t2r[8],  u3 = *(float4*)&t2r[12];
    float o[4];
    #pragma unroll
    for (int i = 0; i < 4; ++i) {
      const float* w2r = &sw2[p][(h3 + 4 * i) * 16];
      float acc = 0.f;
      acc = fmaf(w2r[0],  u0.x, acc); acc = fmaf(w2r[1],  u0.y, acc);
      acc = fmaf(w2r[2],  u0.z, acc); acc = fmaf(w2r[3],  u0.w, acc);
      acc = fmaf(w2r[4],  u1.x, acc); acc = fmaf(w2r[5],  u1.y, acc);
      acc = fmaf(w2r[6],  u1.z, acc); acc = fmaf(w2r[7],  u1.w, acc);
      acc = fmaf(w2r[8],  u2.x, acc); acc = fmaf(w2r[9],  u2.y, acc);
      acc = fmaf(w2r[10], u2.z, acc); acc = fmaf(w2r[11], u2.w, acc);
      acc = fmaf(w2r[12], u3.x, acc); acc = fmaf(w2r[13], u3.y, acc);
      acc = fmaf(w2r[14], u3.z, acc); acc = fmaf(w2r[15], u3.w, acc);
      o[i] = acc + biases[p][r16 * 16 + h3 + 4 * i];
    }
    union { _Float16 hh[4]; uint2 u; } pk;
    const float sc = (p == 0) ? SCALE : 1.0f;
    pk.hh[0] = (_Float16)(o[0] * sc); pk.hh[1] = (_Float16)(o[1] * sc);
    pk.hh[2] = (_Float16)(o[2] * sc); pk.hh[3] = (_Float16)(o[3] * sc);
    *(uint2*)&outs[p][ooff] = pk.u;
    // next p's stage-1 write to t1 is fenced by the stage-1 __syncthreads:
    // this thread's t2 reads complete before it passes that barrier.
    __syncthreads();
  }
}

// ---------------------------------------------------------------------------
// Kernel A2: V [b,h,600,64] f16 -> Vt [b,h,64,600] f16. 64x64 LDS tiles,
// coalesced read AND write; XOR swizzle (r^(r>>3))&7 on 16B chunks makes the
// column gather conflict-free.
// ---------------------------------------------------------------------------
__global__ __launch_bounds__(256) void vtrans_kernel(
    const _Float16* __restrict__ Vh, _Float16* __restrict__ Vt)
{
  __shared__ __align__(16) _Float16 tile[64 * 64];
  const int tid = threadIdx.x;
  const int tt = blockIdx.x, h = blockIdx.y, b = blockIdx.z;
  const size_t rbase = (size_t)(b * NH + h) * S * HD;   // V row-major
  const size_t wbase = (size_t)(b * NH + h) * HD * S;   // Vt
  const int t0 = tt * 64;

  #pragma unroll
  for (int hp = 0; hp < 2; ++hp) {
    const int u = hp * 256 + tid;
    const int r = u >> 3, ch = u & 7;
    f16x8 v = {0, 0, 0, 0, 0, 0, 0, 0};
    if (t0 + r < S) v = *(const f16x8*)&Vh[rbase + (size_t)(t0 + r) * HD + ch * 8];
    *(f16x8*)&tile[r * 64 + ((ch ^ ((r ^ (r >> 3)) & 7)) * 8)] = v;
  }
  __syncthreads();
  #pragma unroll
  for (int hp = 0; hp < 2; ++hp) {
    const int w = hp * 256 + tid;
    const int d = w >> 3, tc = w & 7;
    if (t0 + tc * 8 + 8 <= S) {   // 600 % 8 == 0: chunks are full-or-none
      const int cd = d >> 3;
      union { _Float16 hh[8]; f16x8 v; } g;
      #pragma unroll
      for (int e = 0; e < 8; ++e) {
        const int r = tc * 8 + e;
        g.hh[e] = tile[r * 64 + ((cd ^ ((r ^ (r >> 3)) & 7)) * 8) + (d & 7)];
      }
      *(f16x8*)&Vt[wbase + (size_t)d * S + t0 + tc * 8] = g.v;
    }
  }
}

// ---------------------------------------------------------------------------
// Kernel B: MFMA flash attention (unchanged from R4's passing version).
// ---------------------------------------------------------------------------
__global__ __launch_bounds__(256) void attn_mfma_kernel(
    const _Float16* __restrict__ Qh, const _Float16* __restrict__ Kh,
    const _Float16* __restrict__ Vt, float* __restrict__ Og)
{
  __shared__ __align__(16) union {
    struct {
      _Float16 K[64 * 64];      // swizzled [key][d]
      _Float16 V[64 * 64];      // swizzled [d][key] (tile of Vt)
      _Float16 P[4][16 * 64];   // per-wave swizzled [qrow][key]
    } m;
    float ot[4][64 * 17];       // epilogue per-wave O^T staging
  } sm;

  const int tid = threadIdx.x;
  const int lane = tid & 63;
  const int wv = tid >> 6;
  const int qt = blockIdx.x, h = blockIdx.y, b = blockIdx.z;
  const size_t base  = (size_t)(b * NH + h) * S * HD;   // Q,K,O
  const size_t vbase = (size_t)(b * NH + h) * HD * S;   // Vt
  const int lr = lane & 15;   // row/col-in-16
  const int lg = lane >> 4;   // k-group

  const int qrow_l = qt * 64 + wv * 16 + lr;
  const int qrow = (qrow_l < S) ? qrow_l : (S - 1);
  f16x8 qf0 = *(const f16x8*)&Qh[base + (size_t)qrow * HD + lg * 8];
  f16x8 qf1 = *(const f16x8*)&Qh[base + (size_t)qrow * HD + 32 + lg * 8];

  f32x4 po[4] = {{0.f,0.f,0.f,0.f},{0.f,0.f,0.f,0.f},
                 {0.f,0.f,0.f,0.f},{0.f,0.f,0.f,0.f}};
  float mrow = -1e30f, lrow = 0.f;

  for (int kt = 0; kt < 10; ++kt) {
    const int kb = kt * 64;
    __syncthreads();   // previous tile fully consumed
    #pragma unroll
    for (int hp = 0; hp < 2; ++hp) {
      const int u = hp * 256 + tid;
      const int row = u >> 3, ch = u & 7;
      const int swz = ((ch ^ (row & 7)) * 8);
      f16x8 kv = {0,0,0,0,0,0,0,0};
      if (kb + row < S)
        kv = *(const f16x8*)&Kh[base + (size_t)(kb + row) * HD + ch * 8];
      *(f16x8*)&sm.m.K[row * 64 + swz] = kv;
      f16x8 vv = {0,0,0,0,0,0,0,0};
      if (kb + ch * 8 + 8 <= S)
        vv = *(const f16x8*)&Vt[vbase + (size_t)row * S + kb + ch * 8];
      *(f16x8*)&sm.m.V[row * 64 + swz] = vv;
    }
    __syncthreads();

    // --- S^T: keys (rows) x 16 q-cols ---
    f32x4 accs[4] = {{0.f,0.f,0.f,0.f},{0.f,0.f,0.f,0.f},
                     {0.f,0.f,0.f,0.f},{0.f,0.f,0.f,0.f}};
    #pragma unroll
    for (int c = 0; c < 2; ++c) {
      const f16x8 qf = c ? qf1 : qf0;
      #pragma unroll
      for (int mt = 0; mt < 4; ++mt) {
        const int krow = mt * 16 + lr;
        const f16x8 kf = *(const f16x8*)
            &sm.m.K[krow * 64 + (((4 * c + lg) ^ (krow & 7)) * 8)];
        accs[mt] = __builtin_amdgcn_mfma_f32_16x16x32_f16(kf, qf, accs[mt], 0, 0, 0);
      }
    }

    // --- online softmax (lane owns q-row lr) ---
    float sv[4][4];
    float tmax = -1e30f;
    #pragma unroll
    for (int mt = 0; mt < 4; ++mt)
      #pragma unroll
      for (int r = 0; r < 4; ++r) {
        float s = accs[mt][r];
        if (kb + mt * 16 + 4 * lg + r >= S) s = -1e30f;
        sv[mt][r] = s;
        tmax = fmaxf(tmax, s);
      }
    tmax = fmaxf(tmax, __shfl_xor(tmax, 16));
    tmax = fmaxf(tmax, __shfl_xor(tmax, 32));
    const float mn = fmaxf(mrow, tmax);
    const float corr = __expf(mrow - mn);
    float rs = 0.f;
    _Float16 ph[4][4];
    #pragma unroll
    for (int mt = 0; mt < 4; ++mt)
      #pragma unroll
      for (int r = 0; r < 4; ++r) {
        const float pv = __expf(sv[mt][r] - mn);
        rs += pv;
        ph[mt][r] = (_Float16)pv;
      }
    rs += __shfl_xor(rs, 16);
    rs += __shfl_xor(rs, 32);
    lrow = lrow * corr + rs;
    mrow = mn;
    #pragma unroll
    for (int dt = 0; dt < 4; ++dt) {
      po[dt][0] *= corr; po[dt][1] *= corr;
      po[dt][2] *= corr; po[dt][3] *= corr;
    }

    // --- P -> per-wave swizzled LDS ---
    #pragma unroll
    for (int mt = 0; mt < 4; ++mt) {
      union { _Float16 hh[4]; unsigned long long u; } pk;
      pk.hh[0] = ph[mt][0]; pk.hh[1] = ph[mt][1];
      pk.hh[2] = ph[mt][2]; pk.hh[3] = ph[mt][3];
      const int idx = lr * 64 + (((2 * mt + (lg >> 1)) ^ (lr & 7)) * 8)
                    + (lg & 1) * 4;
      *(unsigned long long*)&sm.m.P[wv][idx] = pk.u;
    }
    __builtin_amdgcn_wave_barrier();   // fence: P writes before P reads (same wave)

    // --- O^T += V^T * P^T ---
    #pragma unroll
    for (int c = 0; c < 2; ++c) {
      const f16x8 pf = *(const f16x8*)
          &sm.m.P[wv][lr * 64 + (((4 * c + lg) ^ (lr & 7)) * 8)];
      #pragma unroll
      for (int dt = 0; dt < 4; ++dt) {
        const int drow = dt * 16 + lr;
        const f16x8 vf = *(const f16x8*)
            &sm.m.V[drow * 64 + (((4 * c + lg) ^ (drow & 7)) * 8)];
        po[dt] = __builtin_amdgcn_mfma_f32_16x16x32_f16(vf, pf, po[dt], 0, 0, 0);
      }
    }
  }

  __syncthreads();   // main-loop LDS fully consumed before epilogue reuse

  const float invl = 1.0f / lrow;
  #pragma unroll
  for (int dt = 0; dt < 4; ++dt)
    #pragma unroll
    for (int r = 0; r < 4; ++r)
      sm.ot[wv][(dt * 16 + 4 * lg + r) * 17 + lr] = po[dt][r] * invl;
  __builtin_amdgcn_wave_barrier();   // fence: ot writes before ot reads (same wave)
  #pragma unroll
  for (int ps = 0; ps < 4; ++ps) {
    const int qr = ps * 4 + lg;
    const int gq = qt * 64 + wv * 16 + qr;
    if (gq < S) {
      const int d0 = lr * 4;
      float4 o4;
      o4.x = sm.ot[wv][(d0 + 0) * 17 + qr];
      o4.y = sm.ot[wv][(d0 + 1) * 17 + qr];
      o4.z = sm.ot[wv][(d0 + 2) * 17 + qr];
      o4.w = sm.ot[wv][(d0 + 3) * 17 + qr];
      *(float4*)&Og[base + (size_t)gq * HD + d0] = o4;
    }
  }
}

// ---------------------------------------------------------------------------
// Kernel C: gather heads -> merged embed, then TCL with o weights -> d_out.
// ---------------------------------------------------------------------------
__global__ __launch_bounds__(256) void tcl_out_kernel(
    const float* __restrict__ Og,
    const float* __restrict__ ow0, const float* __restrict__ ow1,
    const float* __restrict__ ow2, const float* __restrict__ ob,
    float* __restrict__ out)
{
  __shared__ __align__(16) float sx[1024];
  __shared__ __align__(16) float t1[64 * LDT];
  __shared__ __align__(16) float t2[64 * LDT];
  __shared__ float sw0[64], sw1[64], sw2[256];

  const int tid = threadIdx.x;
  const int t = blockIdx.x, b = blockIdx.y;

  {
    const int h = tid >> 4, dimq = tid & 15;
    const int xs = dimq >> 2, ys = dimq & 3;
    const int aa = 2 * xs + (h >> 3), cc = 2 * ys + ((h >> 2) & 1), h3 = h & 3;
    const float4 v = *(const float4*)&Og[((size_t)(b * NH + h) * S + t) * HD + dimq * 4];
    float* sr = &sx[(aa * 8 + cc) * 16 + h3];
    sr[0] = v.x; sr[4] = v.y; sr[8] = v.z; sr[12] = v.w;
  }
  if (tid < 64) { sw0[tid] = ow0[tid]; sw1[tid] = ow1[tid]; }
  sw2[tid] = ow2[tid];
  __syncthreads();

  const int a = tid >> 5, c = (tid >> 2) & 7, dq = tid & 3;

  float4 r = make_float4(0.f, 0.f, 0.f, 0.f);
  #pragma unroll
  for (int xx = 0; xx < 8; ++xx) {
    const float w = sw0[a * 8 + xx];
    const float4 v = *(float4*)&sx[xx * 128 + c * 16 + dq * 4];
    fma4(r, w, v);
  }
  *(float4*)&t1[(a * 8 + c) * LDT + dq * 4] = r;
  __syncthreads();
  r = make_float4(0.f, 0.f, 0.f, 0.f);
  #pragma unroll
  for (int yy = 0; yy < 8; ++yy) {
    const float w = sw1[c * 8 + yy];
    const float4 v = *(float4*)&t1[(a * 8 + yy) * LDT + dq * 4];
    fma4(r, w, v);
  }
  *(float4*)&t2[(a * 8 + c) * LDT + dq * 4] = r;
  __syncthreads();
  const float* t2r = &t2[(a * 8 + c) * LDT];
  const float4 u0 = *(float4*)&t2r[0],  u1 = *(float4*)&t2r[4];
  const float4 u2 = *(float4*)&t2r[8],  u3 = *(float4*)&t2r[12];
  const float4 bias4 = *(const float4*)&ob[(a * 8 + c) * 16 + dq * 4];
  float o[4];
  #pragma unroll
  for (int i = 0; i < 4; ++i) {
    const float* w2r = &sw2[(dq * 4 + i) * 16];
    float acc = 0.f;
    acc = fmaf(w2r[0],  u0.x, acc); acc = fmaf(w2r[1],  u0.y, acc);
    acc = fmaf(w2r[2],  u0.z, acc); acc = fmaf(w2r[3],  u0.w, acc);
    acc = fmaf(w2r[4],  u1.x, acc); acc = fmaf(w2r[5],  u1.y, acc);
    acc = fmaf(w2r[6],  u1.z, acc); acc = fmaf(w2r[7],  u1.w, acc);
    acc = fmaf(w2r[8],  u2.x, acc); acc = fmaf(w2r[9],  u2.y, acc);
    acc = fmaf(w2r[10], u2.z, acc); acc = fmaf(w2r[11], u2.w, acc);
    acc = fmaf(w2r[12], u3.x, acc); acc = fmaf(w2r[13], u3.y, acc);
    acc = fmaf(w2r[14], u3.z, acc); acc = fmaf(w2r[15], u3.w, acc);
    o[i] = acc;
  }
  const float4 res = make_float4(o[0] + bias4.x, o[1] + bias4.y,
                                 o[2] + bias4.z, o[3] + bias4.w);
  *(float4*)&out[((size_t)(b * S + t)) * 1024 + (a * 8 + c) * 16 + dq * 4] = res;
}

// ---------------------------------------------------------------------------
extern "C" void kernel_launch(void* const* d_in, const int* in_sizes, int n_in,
                              void* d_out, int out_size, void* d_ws, size_t ws_size,
                              hipStream_t stream) {
  const float* x   = (const float*)d_in[0];
  const float* qw0 = (const float*)d_in[1];
  const float* qw1 = (const float*)d_in[2];
  const float* qw2 = (const float*)d_in[3];
  const float* qb  = (const float*)d_in[4];
  const float* kw0 = (const float*)d_in[5];
  const float* kw1 = (const float*)d_in[6];
  const float* kw2 = (const float*)d_in[7];
  const float* kb  = (const float*)d_in[8];
  const float* vw0 = (const float*)d_in[9];
  const float* vw1 = (const float*)d_in[10];
  const float* vw2 = (const float*)d_in[11];
  const float* vb  = (const float*)d_in[12];
  const float* ow0 = (const float*)d_in[13];
  const float* ow1 = (const float*)d_in[14];
  const float* ow2 = (const float*)d_in[15];
  const float* ob  = (const float*)d_in[16];

  const size_t N = (size_t)NB * NH * S * HD;  // 9,830,400 elems per logical buffer
  _Float16* Qh  = (_Float16*)d_ws;
  _Float16* Kh  = Qh + N;
  _Float16* Vth = Kh + N;
  // Region X at 3N f16-elems (16B-aligned): first used as row-major V temp
  // (N f16), then reused as O (N f32). V is dead before attn writes O.
  _Float16* Vh  = Vth + N;
  float*    O   = (float*)Vh;
  // total ws use: 3*N*2 + N*4 = 98.3 MB (same footprint R4 ran with)

  tcl_qkv_kernel<<<dim3(S, NB), 256, 0, stream>>>(
      x, qw0, qw1, qw2, qb, kw0, kw1, kw2, kb, vw0, vw1, vw2, vb, Qh, Kh, Vh);
  vtrans_kernel<<<dim3(10, NH, NB), 256, 0, stream>>>(Vh, Vth);
  attn_mfma_kernel<<<dim3(10, NH, NB), 256, 0, stream>>>(Qh, Kh, Vth, O);
  tcl_out_kernel<<<dim3(S, NB), 256, 0, stream>>>(O, ow0, ow1, ow2, ob,
                                                  (float*)d_out);
}

// Round 6
// 170.779 us; speedup vs baseline: 3.3839x; 1.1279x over previous
//
#include <hip/hip_runtime.h>

// Problem constants:
//   B=16, P1=25, P2=24 -> S=600 tokens; E=(8,8,16)=1024; heads (2,2,4)=16, head_dim 64
#define S   600
#define NB  16
#define NH  16
#define HD  64
// Q pre-scale: (head_dim)^-0.5 * log2(e), so attention scores are in log2
// domain and softmax uses v_exp_f32 (= exp2) directly with no per-element mul.
#define QSCALE 0.18033688011112042f

#define LDT 20   // TCL intermediate row stride

typedef _Float16 f16x8 __attribute__((ext_vector_type(8)));
typedef float f32x4 __attribute__((ext_vector_type(4)));

__device__ __forceinline__ void fma4(float4& a, const float p, const float4 v) {
  a.x = fmaf(p, v.x, a.x); a.y = fmaf(p, v.y, a.y);
  a.z = fmaf(p, v.z, a.z); a.w = fmaf(p, v.w, a.w);
}

// ---------------------------------------------------------------------------
// Kernel A: TCL for q,k,v (fp32 compute). Emits f16, ALL row-major coalesced:
//   Qh [b,h,s,64] (pre-scaled by QSCALE), Kh [b,h,s,64], Vh [b,h,s,64].
// ---------------------------------------------------------------------------
__global__ __launch_bounds__(256) void tcl_qkv_kernel(
    const float* __restrict__ x,
    const float* __restrict__ qw0, const float* __restrict__ qw1,
    const float* __restrict__ qw2, const float* __restrict__ qb,
    const float* __restrict__ kw0, const float* __restrict__ kw1,
    const float* __restrict__ kw2, const float* __restrict__ kb,
    const float* __restrict__ vw0, const float* __restrict__ vw1,
    const float* __restrict__ vw2, const float* __restrict__ vb,
    _Float16* __restrict__ Qh, _Float16* __restrict__ Kh,
    _Float16* __restrict__ Vh)
{
  __shared__ __align__(16) float sx[1024];       // [x][y][z] natural
  __shared__ __align__(16) float t1[64 * LDT];
  __shared__ __align__(16) float t2[64 * LDT];
  __shared__ float sw0[3][64], sw1[3][64], sw2[3][256];

  const int tid = threadIdx.x;
  const int t = blockIdx.x, b = blockIdx.y;
  const size_t tok = (size_t)b * S + t;

  *(float4*)&sx[tid * 4] = *(const float4*)&x[tok * 1024 + tid * 4];
  if (tid < 64) {
    sw0[0][tid] = qw0[tid]; sw0[1][tid] = kw0[tid]; sw0[2][tid] = vw0[tid];
    sw1[0][tid] = qw1[tid]; sw1[1][tid] = kw1[tid]; sw1[2][tid] = vw1[tid];
  }
  sw2[0][tid] = qw2[tid]; sw2[1][tid] = kw2[tid]; sw2[2][tid] = vw2[tid];
  __syncthreads();

  const int a = tid >> 5, c = (tid >> 2) & 7, dq = tid & 3;
  const int h = tid >> 4, dimq = tid & 15;
  const int xs = dimq >> 2, ys = dimq & 3;
  const int aa = 2 * xs + (h >> 3), cc = 2 * ys + ((h >> 2) & 1), h3 = h & 3;
  const int r16 = aa * 8 + cc;
  const size_t ooff = ((size_t)(b * NH + h) * S + t) * HD + dimq * 4;

  const float* biases[3] = {qb, kb, vb};
  _Float16* outs[3] = {Qh, Kh, Vh};

  #pragma unroll
  for (int p = 0; p < 3; ++p) {
    float4 r = make_float4(0.f, 0.f, 0.f, 0.f);
    #pragma unroll
    for (int xx = 0; xx < 8; ++xx) {
      const float w = sw0[p][a * 8 + xx];
      const float4 v = *(float4*)&sx[xx * 128 + c * 16 + dq * 4];
      fma4(r, w, v);
    }
    *(float4*)&t1[(a * 8 + c) * LDT + dq * 4] = r;
    __syncthreads();
    r = make_float4(0.f, 0.f, 0.f, 0.f);
    #pragma unroll
    for (int yy = 0; yy < 8; ++yy) {
      const float w = sw1[p][c * 8 + yy];
      const float4 v = *(float4*)&t1[(a * 8 + yy) * LDT + dq * 4];
      fma4(r, w, v);
    }
    *(float4*)&t2[(a * 8 + c) * LDT + dq * 4] = r;
    __syncthreads();
    const float* t2r = &t2[r16 * LDT];
    const float4 u0 = *(float4*)&t2r[0],  u1 = *(float4*)&t2r[4];
    const float4 u2 = *(float4*)&t2r[8],  u3 = *(float4*)&t2r[12];
    float o[4];
    #pragma unroll
    for (int i = 0; i < 4; ++i) {
      const float* w2r = &sw2[p][(h3 + 4 * i) * 16];
      float acc = 0.f;
      acc = fmaf(w2r[0],  u0.x, acc); acc = fmaf(w2r[1],  u0.y, acc);
      acc = fmaf(w2r[2],  u0.z, acc); acc = fmaf(w2r[3],  u0.w, acc);
      acc = fmaf(w2r[4],  u1.x, acc); acc = fmaf(w2r[5],  u1.y, acc);
      acc = fmaf(w2r[6],  u1.z, acc); acc = fmaf(w2r[7],  u1.w, acc);
      acc = fmaf(w2r[8],  u2.x, acc); acc = fmaf(w2r[9],  u2.y, acc);
      acc = fmaf(w2r[10], u2.z, acc); acc = fmaf(w2r[11], u2.w, acc);
      acc = fmaf(w2r[12], u3.x, acc); acc = fmaf(w2r[13], u3.y, acc);
      acc = fmaf(w2r[14], u3.z, acc); acc = fmaf(w2r[15], u3.w, acc);
      o[i] = acc + biases[p][r16 * 16 + h3 + 4 * i];
    }
    union { _Float16 hh[4]; uint2 u; } pk;
    const float sc = (p == 0) ? QSCALE : 1.0f;
    pk.hh[0] = (_Float16)(o[0] * sc); pk.hh[1] = (_Float16)(o[1] * sc);
    pk.hh[2] = (_Float16)(o[2] * sc); pk.hh[3] = (_Float16)(o[3] * sc);
    *(uint2*)&outs[p][ooff] = pk.u;
    __syncthreads();
  }
}

// ---------------------------------------------------------------------------
// Kernel A2: V [b,h,600,64] f16 -> Vt [b,h,64,600] f16.
// ---------------------------------------------------------------------------
__global__ __launch_bounds__(256) void vtrans_kernel(
    const _Float16* __restrict__ Vh, _Float16* __restrict__ Vt)
{
  __shared__ __align__(16) _Float16 tile[64 * 64];
  const int tid = threadIdx.x;
  const int tt = blockIdx.x, h = blockIdx.y, b = blockIdx.z;
  const size_t rbase = (size_t)(b * NH + h) * S * HD;
  const size_t wbase = (size_t)(b * NH + h) * HD * S;
  const int t0 = tt * 64;

  #pragma unroll
  for (int hp = 0; hp < 2; ++hp) {
    const int u = hp * 256 + tid;
    const int r = u >> 3, ch = u & 7;
    f16x8 v = {0, 0, 0, 0, 0, 0, 0, 0};
    if (t0 + r < S) v = *(const f16x8*)&Vh[rbase + (size_t)(t0 + r) * HD + ch * 8];
    *(f16x8*)&tile[r * 64 + ((ch ^ ((r ^ (r >> 3)) & 7)) * 8)] = v;
  }
  __syncthreads();
  #pragma unroll
  for (int hp = 0; hp < 2; ++hp) {
    const int w = hp * 256 + tid;
    const int d = w >> 3, tc = w & 7;
    if (t0 + tc * 8 + 8 <= S) {
      const int cd = d >> 3;
      union { _Float16 hh[8]; f16x8 v; } g;
      #pragma unroll
      for (int e = 0; e < 8; ++e) {
        const int r = tc * 8 + e;
        g.hh[e] = tile[r * 64 + ((cd ^ ((r ^ (r >> 3)) & 7)) * 8) + (d & 7)];
      }
      *(f16x8*)&Vt[wbase + (size_t)d * S + t0 + tc * 8] = g.v;
    }
  }
}

// ---------------------------------------------------------------------------
// Kernel B: MFMA flash attention. 1-D grid 2560, XCD-aware decode so all 10
// q-tiles of one (b,h) share an XCD (L2 reuse of K/V). Double-buffered K/V
// staging with one barrier per tile; next tile's global loads issued before
// current tile's compute (latency hidden under MFMA+softmax).
// Softmax in log2 domain (Q pre-scaled by QSCALE), defer-max rescale (THR=11
// -> P <= 2^11, safe in f16), balanced reduce trees, mask only on last tile.
// ---------------------------------------------------------------------------
template<bool TAIL>
__device__ __forceinline__ void attn_step(
    const _Float16* __restrict__ Ks, const _Float16* __restrict__ Vs,
    _Float16* __restrict__ Pw,
    const f16x8 qf0, const f16x8 qf1,
    f32x4 (&po)[4], float& mrow, float& lrow,
    const int lr, const int lg)
{
  constexpr int NMT = TAIL ? 2 : 4;   // key sub-tiles (tail: keys >= 608 dead)
  f32x4 accs[NMT];
  #pragma unroll
  for (int mt = 0; mt < NMT; ++mt) accs[mt] = (f32x4){0.f, 0.f, 0.f, 0.f};
  #pragma unroll
  for (int c = 0; c < 2; ++c) {
    const f16x8 qf = c ? qf1 : qf0;
    #pragma unroll
    for (int mt = 0; mt < NMT; ++mt) {
      const int krow = mt * 16 + lr;
      const f16x8 kf = *(const f16x8*)
          &Ks[krow * 64 + (((4 * c + lg) ^ (krow & 7)) * 8)];
      accs[mt] = __builtin_amdgcn_mfma_f32_16x16x32_f16(kf, qf, accs[mt], 0, 0, 0);
    }
  }
  // lane (lr,lg) holds scores of q-row lr for keys mt*16+4*lg+r
  float sv[NMT][4];
  #pragma unroll
  for (int mt = 0; mt < NMT; ++mt)
    #pragma unroll
    for (int r = 0; r < 4; ++r) {
      float s = accs[mt][r];
      if (TAIL && mt == 1) s = (lg < 2) ? s : -1e30f;  // keys 600..607 dead
      sv[mt][r] = s;
    }
  float tmax;
  {
    const float a = fmaxf(fmaxf(sv[0][0], sv[0][1]), fmaxf(sv[0][2], sv[0][3]));
    const float b = fmaxf(fmaxf(sv[1][0], sv[1][1]), fmaxf(sv[1][2], sv[1][3]));
    if (TAIL) {
      tmax = fmaxf(a, b);
    } else {
      const float c2 = fmaxf(fmaxf(sv[2][0], sv[2][1]), fmaxf(sv[2][2], sv[2][3]));
      const float d2 = fmaxf(fmaxf(sv[3][0], sv[3][1]), fmaxf(sv[3][2], sv[3][3]));
      tmax = fmaxf(fmaxf(a, b), fmaxf(c2, d2));
    }
  }
  tmax = fmaxf(tmax, __shfl_xor(tmax, 16));
  tmax = fmaxf(tmax, __shfl_xor(tmax, 32));
  // defer-max: skip O/l rescale while tile max is within 2^11 of running max
  if (!__all(tmax - mrow <= 11.0f)) {
    const float mn = fmaxf(mrow, tmax);
    const float corr = __builtin_amdgcn_exp2f(mrow - mn);
    lrow *= corr;
    #pragma unroll
    for (int dt = 0; dt < 4; ++dt) {
      po[dt][0] *= corr; po[dt][1] *= corr;
      po[dt][2] *= corr; po[dt][3] *= corr;
    }
    mrow = mn;
  }
  _Float16 ph[NMT][4];
  float rsv[NMT];
  #pragma unroll
  for (int mt = 0; mt < NMT; ++mt) {
    const float e0 = __builtin_amdgcn_exp2f(sv[mt][0] - mrow);
    const float e1 = __builtin_amdgcn_exp2f(sv[mt][1] - mrow);
    const float e2 = __builtin_amdgcn_exp2f(sv[mt][2] - mrow);
    const float e3 = __builtin_amdgcn_exp2f(sv[mt][3] - mrow);
    ph[mt][0] = (_Float16)e0; ph[mt][1] = (_Float16)e1;
    ph[mt][2] = (_Float16)e2; ph[mt][3] = (_Float16)e3;
    rsv[mt] = (e0 + e1) + (e2 + e3);
  }
  float rs = TAIL ? (rsv[0] + rsv[1]) : ((rsv[0] + rsv[1]) + (rsv[2] + rsv[3]));
  rs += __shfl_xor(rs, 16);
  rs += __shfl_xor(rs, 32);
  lrow += rs;
  // P relay: per-wave swizzled LDS (keys mt*16+4*lg+0..3 at row lr)
  #pragma unroll
  for (int mt = 0; mt < NMT; ++mt) {
    union { _Float16 hh[4]; unsigned long long u; } pk;
    pk.hh[0] = ph[mt][0]; pk.hh[1] = ph[mt][1];
    pk.hh[2] = ph[mt][2]; pk.hh[3] = ph[mt][3];
    const int idx = lr * 64 + (((2 * mt + (lg >> 1)) ^ (lr & 7)) * 8)
                  + (lg & 1) * 4;
    *(unsigned long long*)&Pw[idx] = pk.u;
  }
  __builtin_amdgcn_wave_barrier();   // fence: P writes before P reads (same wave)
  #pragma unroll
  for (int c = 0; c < (TAIL ? 1 : 2); ++c) {
    const f16x8 pf = *(const f16x8*)&Pw[lr * 64 + (((4 * c + lg) ^ (lr & 7)) * 8)];
    #pragma unroll
    for (int dt = 0; dt < 4; ++dt) {
      const int drow = dt * 16 + lr;
      const f16x8 vf = *(const f16x8*)
          &Vs[drow * 64 + (((4 * c + lg) ^ (drow & 7)) * 8)];
      po[dt] = __builtin_amdgcn_mfma_f32_16x16x32_f16(vf, pf, po[dt], 0, 0, 0);
    }
  }
}

__global__ __launch_bounds__(256) void attn_mfma_kernel(
    const _Float16* __restrict__ Qh, const _Float16* __restrict__ Kh,
    const _Float16* __restrict__ Vt, float* __restrict__ Og)
{
  __shared__ __align__(16) union {
    struct {
      _Float16 K[2][64 * 64];   // double-buffered, swizzled [key][d]
      _Float16 V[2][64 * 64];   // double-buffered, swizzled [d][key]
      _Float16 P[4][16 * 64];   // per-wave swizzled [qrow][key]
    } m;
    float ot[4][64 * 17];       // epilogue per-wave O^T staging
  } sm;

  const int tid = threadIdx.x;
  const int lane = tid & 63;
  const int wv = tid >> 6;
  // XCD-aware decode: 2560 blocks; xcd = id%8 (round-robin dispatch), each
  // XCD owns 32 consecutive (b,h) groups; all 10 q-tiles of a (b,h) co-locate.
  const int id = blockIdx.x;
  const int idx = id >> 3;
  const int bh = (id & 7) * 32 + idx / 10;
  const int qt = idx - (idx / 10) * 10;
  const size_t base  = (size_t)bh * S * HD;   // Q,K,O
  const size_t vbase = (size_t)bh * HD * S;   // Vt
  const int lr = lane & 15;
  const int lg = lane >> 4;

  const int qrow_l = qt * 64 + wv * 16 + lr;
  const int qrow = (qrow_l < S) ? qrow_l : (S - 1);
  const f16x8 qf0 = *(const f16x8*)&Qh[base + (size_t)qrow * HD + lg * 8];
  const f16x8 qf1 = *(const f16x8*)&Qh[base + (size_t)qrow * HD + 32 + lg * 8];

  f32x4 po[4] = {{0.f,0.f,0.f,0.f},{0.f,0.f,0.f,0.f},
                 {0.f,0.f,0.f,0.f},{0.f,0.f,0.f,0.f}};
  float mrow = -1e30f, lrow = 0.f;

  const int srow = tid >> 3, sch = tid & 7;          // staging: row, 16B chunk
  const int sswz = ((sch ^ (srow & 7)) * 8);
  const int srow2 = (256 + tid) >> 3;                // second half (rows 32..63)
  const int sswz2 = ((sch ^ (srow2 & 7)) * 8);

  auto stage_load = [&](int kt, f16x8* kv, f16x8* vv) {
    const int kb = kt * 64;
    f16x8 z = {0, 0, 0, 0, 0, 0, 0, 0};
    kv[0] = z; kv[1] = z; vv[0] = z; vv[1] = z;
    if (kb + srow  < S) kv[0] = *(const f16x8*)&Kh[base + (size_t)(kb + srow ) * HD + sch * 8];
    if (kb + srow2 < S) kv[1] = *(const f16x8*)&Kh[base + (size_t)(kb + srow2) * HD + sch * 8];
    if (kb + sch * 8 + 8 <= S) {
      vv[0] = *(const f16x8*)&Vt[vbase + (size_t)srow  * S + kb + sch * 8];
      vv[1] = *(const f16x8*)&Vt[vbase + (size_t)srow2 * S + kb + sch * 8];
    }
  };
  auto stage_write = [&](int buf, const f16x8* kv, const f16x8* vv) {
    *(f16x8*)&sm.m.K[buf][srow  * 64 + sswz ] = kv[0];
    *(f16x8*)&sm.m.K[buf][srow2 * 64 + sswz2] = kv[1];
    *(f16x8*)&sm.m.V[buf][srow  * 64 + sswz ] = vv[0];
    *(f16x8*)&sm.m.V[buf][srow2 * 64 + sswz2] = vv[1];
  };

  f16x8 kv[2], vv[2];
  stage_load(0, kv, vv);
  stage_write(0, kv, vv);
  __syncthreads();

  // One barrier per tile: iter kt reads buf[kt&1] (filled before the previous
  // barrier) and writes buf[1-(kt&1)] (last read two barriers ago) -> no
  // read/write overlap without a barrier between them.
  #pragma unroll 1
  for (int kt = 0; kt < 9; ++kt) {
    const int cur = kt & 1;
    stage_load(kt + 1, kv, vv);          // global loads in flight over compute
    attn_step<false>(&sm.m.K[cur][0], &sm.m.V[cur][0], &sm.m.P[wv][0],
                     qf0, qf1, po, mrow, lrow, lr, lg);
    stage_write(cur ^ 1, kv, vv);
    __syncthreads();
  }
  attn_step<true>(&sm.m.K[1][0], &sm.m.V[1][0], &sm.m.P[wv][0],
                  qf0, qf1, po, mrow, lrow, lr, lg);   // kt=9 (cur=1)
  __syncthreads();   // main-loop LDS fully consumed before epilogue reuse

  const float invl = 1.0f / lrow;
  #pragma unroll
  for (int dt = 0; dt < 4; ++dt)
    #pragma unroll
    for (int r = 0; r < 4; ++r)
      sm.ot[wv][(dt * 16 + 4 * lg + r) * 17 + lr] = po[dt][r] * invl;
  __builtin_amdgcn_wave_barrier();   // fence: ot writes before ot reads (same wave)
  #pragma unroll
  for (int ps = 0; ps < 4; ++ps) {
    const int qr = ps * 4 + lg;
    const int gq = qt * 64 + wv * 16 + qr;
    if (gq < S) {
      const int d0 = lr * 4;
      float4 o4;
      o4.x = sm.ot[wv][(d0 + 0) * 17 + qr];
      o4.y = sm.ot[wv][(d0 + 1) * 17 + qr];
      o4.z = sm.ot[wv][(d0 + 2) * 17 + qr];
      o4.w = sm.ot[wv][(d0 + 3) * 17 + qr];
      *(float4*)&Og[base + (size_t)gq * HD + d0] = o4;
    }
  }
}

// ---------------------------------------------------------------------------
// Kernel C: gather heads -> merged embed, then TCL with o weights -> d_out.
// ---------------------------------------------------------------------------
__global__ __launch_bounds__(256) void tcl_out_kernel(
    const float* __restrict__ Og,
    const float* __restrict__ ow0, const float* __restrict__ ow1,
    const float* __restrict__ ow2, const float* __restrict__ ob,
    float* __restrict__ out)
{
  __shared__ __align__(16) float sx[1024];
  __shared__ __align__(16) float t1[64 * LDT];
  __shared__ __align__(16) float t2[64 * LDT];
  __shared__ float sw0[64], sw1[64], sw2[256];

  const int tid = threadIdx.x;
  const int t = blockIdx.x, b = blockIdx.y;

  {
    const int h = tid >> 4, dimq = tid & 15;
    const int xs = dimq >> 2, ys = dimq & 3;
    const int aa = 2 * xs + (h >> 3), cc = 2 * ys + ((h >> 2) & 1), h3 = h & 3;
    const float4 v = *(const float4*)&Og[((size_t)(b * NH + h) * S + t) * HD + dimq * 4];
    float* sr = &sx[(aa * 8 + cc) * 16 + h3];
    sr[0] = v.x; sr[4] = v.y; sr[8] = v.z; sr[12] = v.w;
  }
  if (tid < 64) { sw0[tid] = ow0[tid]; sw1[tid] = ow1[tid]; }
  sw2[tid] = ow2[tid];
  __syncthreads();

  const int a = tid >> 5, c = (tid >> 2) & 7, dq = tid & 3;

  float4 r = make_float4(0.f, 0.f, 0.f, 0.f);
  #pragma unroll
  for (int xx = 0; xx < 8; ++xx) {
    const float w = sw0[a * 8 + xx];
    const float4 v = *(float4*)&sx[xx * 128 + c * 16 + dq * 4];
    fma4(r, w, v);
  }
  *(float4*)&t1[(a * 8 + c) * LDT + dq * 4] = r;
  __syncthreads();
  r = make_float4(0.f, 0.f, 0.f, 0.f);
  #pragma unroll
  for (int yy = 0; yy < 8; ++yy) {
    const float w = sw1[c * 8 + yy];
    const float4 v = *(float4*)&t1[(a * 8 + yy) * LDT + dq * 4];
    fma4(r, w, v);
  }
  *(float4*)&t2[(a * 8 + c) * LDT + dq * 4] = r;
  __syncthreads();
  const float* t2r = &t2[(a * 8 + c) * LDT];
  const float4 u0 = *(float4*)&t2r[0],  u1 = *(float4*)&t2r[4];
  const float4 u2 = *(float4*)&t2r[8],  u3 = *(float4*)&t2r[12];
  const float4 bias4 = *(const float4*)&ob[(a * 8 + c) * 16 + dq * 4];
  float o[4];
  #pragma unroll
  for (int i = 0; i < 4; ++i) {
    const float* w2r = &sw2[(dq * 4 + i) * 16];
    float acc = 0.f;
    acc = fmaf(w2r[0],  u0.x, acc); acc = fmaf(w2r[1],  u0.y, acc);
    acc = fmaf(w2r[2],  u0.z, acc); acc = fmaf(w2r[3],  u0.w, acc);
    acc = fmaf(w2r[4],  u1.x, acc); acc = fmaf(w2r[5],  u1.y, acc);
    acc = fmaf(w2r[6],  u1.z, acc); acc = fmaf(w2r[7],  u1.w, acc);
    acc = fmaf(w2r[8],  u2.x, acc); acc = fmaf(w2r[9],  u2.y, acc);
    acc = fmaf(w2r[10], u2.z, acc); acc = fmaf(w2r[11], u2.w, acc);
    acc = fmaf(w2r[12], u3.x, acc); acc = fmaf(w2r[13], u3.y, acc);
    acc = fmaf(w2r[14], u3.z, acc); acc = fmaf(w2r[15], u3.w, acc);
    o[i] = acc;
  }
  const float4 res = make_float4(o[0] + bias4.x, o[1] + bias4.y,
                                 o[2] + bias4.z, o[3] + bias4.w);
  *(float4*)&out[((size_t)(b * S + t)) * 1024 + (a * 8 + c) * 16 + dq * 4] = res;
}

// ---------------------------------------------------------------------------
extern "C" void kernel_launch(void* const* d_in, const int* in_sizes, int n_in,
                              void* d_out, int out_size, void* d_ws, size_t ws_size,
                              hipStream_t stream) {
  const float* x   = (const float*)d_in[0];
  const float* qw0 = (const float*)d_in[1];
  const float* qw1 = (const float*)d_in[2];
  const float* qw2 = (const float*)d_in[3];
  const float* qb  = (const float*)d_in[4];
  const float* kw0 = (const float*)d_in[5];
  const float* kw1 = (const float*)d_in[6];
  const float* kw2 = (const float*)d_in[7];
  const float* kb  = (const float*)d_in[8];
  const float* vw0 = (const float*)d_in[9];
  const float* vw1 = (const float*)d_in[10];
  const float* vw2 = (const float*)d_in[11];
  const float* vb  = (const float*)d_in[12];
  const float* ow0 = (const float*)d_in[13];
  const float* ow1 = (const float*)d_in[14];
  const float* ow2 = (const float*)d_in[15];
  const float* ob  = (const float*)d_in[16];

  const size_t N = (size_t)NB * NH * S * HD;  // 9,830,400 elems per logical buffer
  _Float16* Qh  = (_Float16*)d_ws;
  _Float16* Kh  = Qh + N;
  _Float16* Vth = Kh + N;
  _Float16* Vh  = Vth + N;            // row-major V temp, later reused as O
  float*    O   = (float*)Vh;
  // total ws use: 3*N*2 + N*4 = 98.3 MB

  tcl_qkv_kernel<<<dim3(S, NB), 256, 0, stream>>>(
      x, qw0, qw1, qw2, qb, kw0, kw1, kw2, kb, vw0, vw1, vw2, vb, Qh, Kh, Vh);
  vtrans_kernel<<<dim3(10, NH, NB), 256, 0, stream>>>(Vh, Vth);
  attn_mfma_kernel<<<dim3(2560), 256, 0, stream>>>(Qh, Kh, Vth, O);
  tcl_out_kernel<<<dim3(S, NB), 256, 0, stream>>>(O, ow0, ow1, ow2, ob,
                                                  (float*)d_out);
}

// Round 7
// 126.693 us; speedup vs baseline: 4.5615x; 1.3480x over previous
//
#include <hip/hip_runtime.h>

// Problem constants:
//   B=16, P1=25, P2=24 -> S=600 tokens; E=(8,8,16)=1024; heads (2,2,4)=16, head_dim 64
#define S   600
#define NB  16
#define NH  16
#define HD  64
// Q pre-scale: (head_dim)^-0.5 * log2(e): scores in log2 domain -> softmax uses exp2.
#define QSCALE 0.18033688011112042f

#define LDT 20   // TCL intermediate row stride (floats)

typedef _Float16 f16x8 __attribute__((ext_vector_type(8)));
typedef float f32x4 __attribute__((ext_vector_type(4)));

// ---------------------------------------------------------------------------
// Kernel A: TCL for q,k,v — wave-per-token, barrier-free.
// Lane l = q*8+zp (q in 0..7, zp = z-pair 0..7). Per projection:
//   stage1 (loop a):  t1[a*8+q][2zp..] = sum_x w0[a,x] * Xcol[x]   (w0 s_load)
//   stage2 (loop c):  t2[q*8+c][2zp..] = sum_y w1[c,y] * t1row[y]  (t1row in regs)
//   stage3 (lane=row r16): o[d] = sum_j w2[d,j] * t2row[j] + bias  (w2 s_load)
// Cross-lane exchange via per-wave LDS; in-wave DS ordering + wave_barrier
// fences (no __syncthreads anywhere). Outputs f16 row-major [b,h,s,64].
// ---------------------------------------------------------------------------
__global__ __launch_bounds__(256) void tcl_qkv_kernel(
    const float* __restrict__ x,
    const float* __restrict__ qw0, const float* __restrict__ qw1,
    const float* __restrict__ qw2, const float* __restrict__ qb,
    const float* __restrict__ kw0, const float* __restrict__ kw1,
    const float* __restrict__ kw2, const float* __restrict__ kb,
    const float* __restrict__ vw0, const float* __restrict__ vw1,
    const float* __restrict__ vw2, const float* __restrict__ vb,
    _Float16* __restrict__ Qh, _Float16* __restrict__ Kh,
    _Float16* __restrict__ Vh)
{
  __shared__ __align__(16) float t1s[4][64 * LDT];
  __shared__ __align__(16) float t2s[4][64 * LDT];

  const int tid = threadIdx.x;
  const int wv = tid >> 6, lane = tid & 63;
  const int tok = blockIdx.x * 4 + wv;
  const int b = tok / S, t = tok - b * S;
  const int q = lane >> 3, zp = lane & 7;
  float* __restrict__ t1 = t1s[wv];
  float* __restrict__ t2 = t2s[wv];

  // X column in registers: X[x][q][2zp..2zp+1], coalesced float2 loads.
  float2 xc[8];
  #pragma unroll
  for (int xx = 0; xx < 8; ++xx)
    xc[xx] = *(const float2*)&x[(size_t)tok * 1024 + xx * 128 + q * 16 + zp * 2];

  // stage-3 head mapping (lane = merged row r16 = aa*8+cc)
  const int xs = lane >> 4;            // aa>>1
  const int h1 = (lane >> 3) & 1;      // aa&1
  const int cc = lane & 7;
  const int ys = cc >> 1, h2 = cc & 1;

  const float* W0[3] = {qw0, kw0, vw0};
  const float* W1[3] = {qw1, kw1, vw1};
  const float* W2[3] = {qw2, kw2, vw2};
  const float* BB[3] = {qb, kb, vb};
  _Float16* OUT[3] = {Qh, Kh, Vh};

  #pragma unroll
  for (int p = 0; p < 3; ++p) {
    const float* __restrict__ w0 = W0[p];
    const float* __restrict__ w1 = W1[p];
    const float* __restrict__ w2 = W2[p];
    const float* __restrict__ bb = BB[p];
    _Float16* __restrict__ op = OUT[p];

    // ---- stage 1: contract x (w0 rows wave-uniform -> s_load) ----
    #pragma unroll
    for (int a = 0; a < 8; ++a) {
      float2 r = make_float2(0.f, 0.f);
      #pragma unroll
      for (int xx = 0; xx < 8; ++xx) {
        const float w = w0[a * 8 + xx];
        r.x = fmaf(w, xc[xx].x, r.x);
        r.y = fmaf(w, xc[xx].y, r.y);
      }
      *(float2*)&t1[(a * 8 + q) * LDT + zp * 2] = r;
    }
    __builtin_amdgcn_wave_barrier();   // t1 writes before t1 reads (same wave)

    // ---- stage 2: contract y (q plays 'a'; t1 row-block hoisted to regs) ----
    float2 t1r[8];
    #pragma unroll
    for (int y = 0; y < 8; ++y)
      t1r[y] = *(float2*)&t1[(q * 8 + y) * LDT + zp * 2];
    #pragma unroll
    for (int c = 0; c < 8; ++c) {
      float2 r = make_float2(0.f, 0.f);
      #pragma unroll
      for (int y = 0; y < 8; ++y) {
        const float w = w1[c * 8 + y];
        r.x = fmaf(w, t1r[y].x, r.x);
        r.y = fmaf(w, t1r[y].y, r.y);
      }
      *(float2*)&t2[(q * 8 + c) * LDT + zp * 2] = r;
    }
    __builtin_amdgcn_wave_barrier();   // t2 writes before t2 reads (same wave)

    // ---- stage 3: contract z (lane owns merged row r16 = lane) ----
    float t2r[16];
    #pragma unroll
    for (int k = 0; k < 4; ++k)
      *(float4*)&t2r[k * 4] = *(float4*)&t2[lane * LDT + k * 4];
    float bias[16];
    #pragma unroll
    for (int k = 0; k < 4; ++k)
      *(float4*)&bias[k * 4] = *(const float4*)&bb[lane * 16 + k * 4];
    float o[16];
    #pragma unroll
    for (int d = 0; d < 16; ++d) {
      float acc = 0.f;
      #pragma unroll
      for (int j = 0; j < 16; ++j)
        acc = fmaf(w2[d * 16 + j], t2r[j], acc);   // w2 s_load (uniform)
      o[d] = acc + bias[d];
    }
    // store: head h = h1*8+h2*4+h3, dims xs*16+ys*4+z (z=0..3, d = 4z+h3)
    const float sc = (p == 0) ? QSCALE : 1.0f;
    #pragma unroll
    for (int h3 = 0; h3 < 4; ++h3) {
      union { _Float16 hh[4]; uint2 u; } pk;
      #pragma unroll
      for (int z = 0; z < 4; ++z)
        pk.hh[z] = (_Float16)(o[4 * z + h3] * sc);
      const int head = h1 * 8 + h2 * 4 + h3;
      *(uint2*)&op[((size_t)((b * NH + head) * S + t)) * HD + xs * 16 + ys * 4]
          = pk.u;
    }
    __builtin_amdgcn_wave_barrier();   // t2 reads done before next p's writes
  }
}

// ---------------------------------------------------------------------------
// Kernel A2: V [b,h,600,64] f16 -> Vt [b,h,64,600] f16.
// ---------------------------------------------------------------------------
__global__ __launch_bounds__(256) void vtrans_kernel(
    const _Float16* __restrict__ Vh, _Float16* __restrict__ Vt)
{
  __shared__ __align__(16) _Float16 tile[64 * 64];
  const int tid = threadIdx.x;
  const int tt = blockIdx.x, h = blockIdx.y, b = blockIdx.z;
  const size_t rbase = (size_t)(b * NH + h) * S * HD;
  const size_t wbase = (size_t)(b * NH + h) * HD * S;
  const int t0 = tt * 64;

  #pragma unroll
  for (int hp = 0; hp < 2; ++hp) {
    const int u = hp * 256 + tid;
    const int r = u >> 3, ch = u & 7;
    f16x8 v = {0, 0, 0, 0, 0, 0, 0, 0};
    if (t0 + r < S) v = *(const f16x8*)&Vh[rbase + (size_t)(t0 + r) * HD + ch * 8];
    *(f16x8*)&tile[r * 64 + ((ch ^ ((r ^ (r >> 3)) & 7)) * 8)] = v;
  }
  __syncthreads();
  #pragma unroll
  for (int hp = 0; hp < 2; ++hp) {
    const int w = hp * 256 + tid;
    const int d = w >> 3, tc = w & 7;
    if (t0 + tc * 8 + 8 <= S) {
      const int cd = d >> 3;
      union { _Float16 hh[8]; f16x8 v; } g;
      #pragma unroll
      for (int e = 0; e < 8; ++e) {
        const int r = tc * 8 + e;
        g.hh[e] = tile[r * 64 + ((cd ^ ((r ^ (r >> 3)) & 7)) * 8) + (d & 7)];
      }
      *(f16x8*)&Vt[wbase + (size_t)d * S + t0 + tc * 8] = g.v;
    }
  }
}

// ---------------------------------------------------------------------------
// Kernel B: MFMA flash attention (unchanged from R6's passing version).
// ---------------------------------------------------------------------------
template<bool TAIL>
__device__ __forceinline__ void attn_step(
    const _Float16* __restrict__ Ks, const _Float16* __restrict__ Vs,
    _Float16* __restrict__ Pw,
    const f16x8 qf0, const f16x8 qf1,
    f32x4 (&po)[4], float& mrow, float& lrow,
    const int lr, const int lg)
{
  constexpr int NMT = TAIL ? 2 : 4;
  f32x4 accs[NMT];
  #pragma unroll
  for (int mt = 0; mt < NMT; ++mt) accs[mt] = (f32x4){0.f, 0.f, 0.f, 0.f};
  #pragma unroll
  for (int c = 0; c < 2; ++c) {
    const f16x8 qf = c ? qf1 : qf0;
    #pragma unroll
    for (int mt = 0; mt < NMT; ++mt) {
      const int krow = mt * 16 + lr;
      const f16x8 kf = *(const f16x8*)
          &Ks[krow * 64 + (((4 * c + lg) ^ (krow & 7)) * 8)];
      accs[mt] = __builtin_amdgcn_mfma_f32_16x16x32_f16(kf, qf, accs[mt], 0, 0, 0);
    }
  }
  float sv[NMT][4];
  #pragma unroll
  for (int mt = 0; mt < NMT; ++mt)
    #pragma unroll
    for (int r = 0; r < 4; ++r) {
      float s = accs[mt][r];
      if (TAIL && mt == 1) s = (lg < 2) ? s : -1e30f;
      sv[mt][r] = s;
    }
  float tmax;
  {
    const float a = fmaxf(fmaxf(sv[0][0], sv[0][1]), fmaxf(sv[0][2], sv[0][3]));
    const float b = fmaxf(fmaxf(sv[1][0], sv[1][1]), fmaxf(sv[1][2], sv[1][3]));
    if (TAIL) {
      tmax = fmaxf(a, b);
    } else {
      const float c2 = fmaxf(fmaxf(sv[2][0], sv[2][1]), fmaxf(sv[2][2], sv[2][3]));
      const float d2 = fmaxf(fmaxf(sv[3][0], sv[3][1]), fmaxf(sv[3][2], sv[3][3]));
      tmax = fmaxf(fmaxf(a, b), fmaxf(c2, d2));
    }
  }
  tmax = fmaxf(tmax, __shfl_xor(tmax, 16));
  tmax = fmaxf(tmax, __shfl_xor(tmax, 32));
  if (!__all(tmax - mrow <= 11.0f)) {
    const float mn = fmaxf(mrow, tmax);
    const float corr = __builtin_amdgcn_exp2f(mrow - mn);
    lrow *= corr;
    #pragma unroll
    for (int dt = 0; dt < 4; ++dt) {
      po[dt][0] *= corr; po[dt][1] *= corr;
      po[dt][2] *= corr; po[dt][3] *= corr;
    }
    mrow = mn;
  }
  _Float16 ph[NMT][4];
  float rsv[NMT];
  #pragma unroll
  for (int mt = 0; mt < NMT; ++mt) {
    const float e0 = __builtin_amdgcn_exp2f(sv[mt][0] - mrow);
    const float e1 = __builtin_amdgcn_exp2f(sv[mt][1] - mrow);
    const float e2 = __builtin_amdgcn_exp2f(sv[mt][2] - mrow);
    const float e3 = __builtin_amdgcn_exp2f(sv[mt][3] - mrow);
    ph[mt][0] = (_Float16)e0; ph[mt][1] = (_Float16)e1;
    ph[mt][2] = (_Float16)e2; ph[mt][3] = (_Float16)e3;
    rsv[mt] = (e0 + e1) + (e2 + e3);
  }
  float rs = TAIL ? (rsv[0] + rsv[1]) : ((rsv[0] + rsv[1]) + (rsv[2] + rsv[3]));
  rs += __shfl_xor(rs, 16);
  rs += __shfl_xor(rs, 32);
  lrow += rs;
  #pragma unroll
  for (int mt = 0; mt < NMT; ++mt) {
    union { _Float16 hh[4]; unsigned long long u; } pk;
    pk.hh[0] = ph[mt][0]; pk.hh[1] = ph[mt][1];
    pk.hh[2] = ph[mt][2]; pk.hh[3] = ph[mt][3];
    const int idx = lr * 64 + (((2 * mt + (lg >> 1)) ^ (lr & 7)) * 8)
                  + (lg & 1) * 4;
    *(unsigned long long*)&Pw[idx] = pk.u;
  }
  __builtin_amdgcn_wave_barrier();
  #pragma unroll
  for (int c = 0; c < (TAIL ? 1 : 2); ++c) {
    const f16x8 pf = *(const f16x8*)&Pw[lr * 64 + (((4 * c + lg) ^ (lr & 7)) * 8)];
    #pragma unroll
    for (int dt = 0; dt < 4; ++dt) {
      const int drow = dt * 16 + lr;
      const f16x8 vf = *(const f16x8*)
          &Vs[drow * 64 + (((4 * c + lg) ^ (drow & 7)) * 8)];
      po[dt] = __builtin_amdgcn_mfma_f32_16x16x32_f16(vf, pf, po[dt], 0, 0, 0);
    }
  }
}

__global__ __launch_bounds__(256) void attn_mfma_kernel(
    const _Float16* __restrict__ Qh, const _Float16* __restrict__ Kh,
    const _Float16* __restrict__ Vt, float* __restrict__ Og)
{
  __shared__ __align__(16) union {
    struct {
      _Float16 K[2][64 * 64];
      _Float16 V[2][64 * 64];
      _Float16 P[4][16 * 64];
    } m;
    float ot[4][64 * 17];
  } sm;

  const int tid = threadIdx.x;
  const int lane = tid & 63;
  const int wv = tid >> 6;
  const int id = blockIdx.x;
  const int idx = id >> 3;
  const int bh = (id & 7) * 32 + idx / 10;
  const int qt = idx - (idx / 10) * 10;
  const size_t base  = (size_t)bh * S * HD;
  const size_t vbase = (size_t)bh * HD * S;
  const int lr = lane & 15;
  const int lg = lane >> 4;

  const int qrow_l = qt * 64 + wv * 16 + lr;
  const int qrow = (qrow_l < S) ? qrow_l : (S - 1);
  const f16x8 qf0 = *(const f16x8*)&Qh[base + (size_t)qrow * HD + lg * 8];
  const f16x8 qf1 = *(const f16x8*)&Qh[base + (size_t)qrow * HD + 32 + lg * 8];

  f32x4 po[4] = {{0.f,0.f,0.f,0.f},{0.f,0.f,0.f,0.f},
                 {0.f,0.f,0.f,0.f},{0.f,0.f,0.f,0.f}};
  float mrow = -1e30f, lrow = 0.f;

  const int srow = tid >> 3, sch = tid & 7;
  const int sswz = ((sch ^ (srow & 7)) * 8);
  const int srow2 = (256 + tid) >> 3;
  const int sswz2 = ((sch ^ (srow2 & 7)) * 8);

  auto stage_load = [&](int kt, f16x8* kv, f16x8* vv) {
    const int kb = kt * 64;
    f16x8 z = {0, 0, 0, 0, 0, 0, 0, 0};
    kv[0] = z; kv[1] = z; vv[0] = z; vv[1] = z;
    if (kb + srow  < S) kv[0] = *(const f16x8*)&Kh[base + (size_t)(kb + srow ) * HD + sch * 8];
    if (kb + srow2 < S) kv[1] = *(const f16x8*)&Kh[base + (size_t)(kb + srow2) * HD + sch * 8];
    if (kb + sch * 8 + 8 <= S) {
      vv[0] = *(const f16x8*)&Vt[vbase + (size_t)srow  * S + kb + sch * 8];
      vv[1] = *(const f16x8*)&Vt[vbase + (size_t)srow2 * S + kb + sch * 8];
    }
  };
  auto stage_write = [&](int buf, const f16x8* kv, const f16x8* vv) {
    *(f16x8*)&sm.m.K[buf][srow  * 64 + sswz ] = kv[0];
    *(f16x8*)&sm.m.K[buf][srow2 * 64 + sswz2] = kv[1];
    *(f16x8*)&sm.m.V[buf][srow  * 64 + sswz ] = vv[0];
    *(f16x8*)&sm.m.V[buf][srow2 * 64 + sswz2] = vv[1];
  };

  f16x8 kv[2], vv[2];
  stage_load(0, kv, vv);
  stage_write(0, kv, vv);
  __syncthreads();

  #pragma unroll 1
  for (int kt = 0; kt < 9; ++kt) {
    const int cur = kt & 1;
    stage_load(kt + 1, kv, vv);
    attn_step<false>(&sm.m.K[cur][0], &sm.m.V[cur][0], &sm.m.P[wv][0],
                     qf0, qf1, po, mrow, lrow, lr, lg);
    stage_write(cur ^ 1, kv, vv);
    __syncthreads();
  }
  attn_step<true>(&sm.m.K[1][0], &sm.m.V[1][0], &sm.m.P[wv][0],
                  qf0, qf1, po, mrow, lrow, lr, lg);
  __syncthreads();

  const float invl = 1.0f / lrow;
  #pragma unroll
  for (int dt = 0; dt < 4; ++dt)
    #pragma unroll
    for (int r = 0; r < 4; ++r)
      sm.ot[wv][(dt * 16 + 4 * lg + r) * 17 + lr] = po[dt][r] * invl;
  __builtin_amdgcn_wave_barrier();
  #pragma unroll
  for (int ps = 0; ps < 4; ++ps) {
    const int qr = ps * 4 + lg;
    const int gq = qt * 64 + wv * 16 + qr;
    if (gq < S) {
      const int d0 = lr * 4;
      float4 o4;
      o4.x = sm.ot[wv][(d0 + 0) * 17 + qr];
      o4.y = sm.ot[wv][(d0 + 1) * 17 + qr];
      o4.z = sm.ot[wv][(d0 + 2) * 17 + qr];
      o4.w = sm.ot[wv][(d0 + 3) * 17 + qr];
      *(float4*)&Og[base + (size_t)gq * HD + d0] = o4;
    }
  }
}

// ---------------------------------------------------------------------------
// Kernel C: output TCL — wave-per-token, barrier-free (same structure as A).
// Input gather: merged m = xx*128 + q*16 + zp*2+j  ->  O[b, head, t, hd] with
//   head = (xx&1)*8 + (q&1)*4 + 2*(zp&1) + j,  hd = (xx>>1)*16 + (q>>1)*4 + (zp>>1).
// Output: f32 merged [token][1024], lane writes its row r16 = lane (4 float4).
// ---------------------------------------------------------------------------
__global__ __launch_bounds__(256) void tcl_out_kernel(
    const float* __restrict__ Og,
    const float* __restrict__ ow0, const float* __restrict__ ow1,
    const float* __restrict__ ow2, const float* __restrict__ ob,
    float* __restrict__ out)
{
  __shared__ __align__(16) float t1s[4][64 * LDT];
  __shared__ __align__(16) float t2s[4][64 * LDT];

  const int tid = threadIdx.x;
  const int wv = tid >> 6, lane = tid & 63;
  const int tok = blockIdx.x * 4 + wv;
  const int b = tok / S, t = tok - b * S;
  const int q = lane >> 3, zp = lane & 7;
  float* __restrict__ t1 = t1s[wv];
  float* __restrict__ t2 = t2s[wv];

  // gather X column (head-split O -> merged column) into registers
  float2 xc[8];
  {
    const int h2g = q & 1, yg = q >> 1;
    const int h3g = 2 * (zp & 1), zg = zp >> 1;
    #pragma unroll
    for (int xx = 0; xx < 8; ++xx) {
      const int headb = (xx & 1) * 8 + h2g * 4 + h3g;
      const size_t off = ((size_t)((b * NH + headb) * S + t)) * HD
                       + (xx >> 1) * 16 + yg * 4 + zg;
      xc[xx].x = Og[off];
      xc[xx].y = Og[off + (size_t)S * HD];   // head+1
    }
  }

  // ---- stage 1 ----
  #pragma unroll
  for (int a = 0; a < 8; ++a) {
    float2 r = make_float2(0.f, 0.f);
    #pragma unroll
    for (int xx = 0; xx < 8; ++xx) {
      const float w = ow0[a * 8 + xx];
      r.x = fmaf(w, xc[xx].x, r.x);
      r.y = fmaf(w, xc[xx].y, r.y);
    }
    *(float2*)&t1[(a * 8 + q) * LDT + zp * 2] = r;
  }
  __builtin_amdgcn_wave_barrier();

  // ---- stage 2 ----
  float2 t1r[8];
  #pragma unroll
  for (int y = 0; y < 8; ++y)
    t1r[y] = *(float2*)&t1[(q * 8 + y) * LDT + zp * 2];
  #pragma unroll
  for (int c = 0; c < 8; ++c) {
    float2 r = make_float2(0.f, 0.f);
    #pragma unroll
    for (int y = 0; y < 8; ++y) {
      const float w = ow1[c * 8 + y];
      r.x = fmaf(w, t1r[y].x, r.x);
      r.y = fmaf(w, t1r[y].y, r.y);
    }
    *(float2*)&t2[(q * 8 + c) * LDT + zp * 2] = r;
  }
  __builtin_amdgcn_wave_barrier();

  // ---- stage 3 ----
  float t2r[16];
  #pragma unroll
  for (int k = 0; k < 4; ++k)
    *(float4*)&t2r[k * 4] = *(float4*)&t2[lane * LDT + k * 4];
  float bias[16];
  #pragma unroll
  for (int k = 0; k < 4; ++k)
    *(float4*)&bias[k * 4] = *(const float4*)&ob[lane * 16 + k * 4];
  float o[16];
  #pragma unroll
  for (int d = 0; d < 16; ++d) {
    float acc = 0.f;
    #pragma unroll
    for (int j = 0; j < 16; ++j)
      acc = fmaf(ow2[d * 16 + j], t2r[j], acc);
    o[d] = acc + bias[d];
  }
  #pragma unroll
  for (int k = 0; k < 4; ++k) {
    const float4 res = make_float4(o[4 * k], o[4 * k + 1],
                                   o[4 * k + 2], o[4 * k + 3]);
    *(float4*)&out[(size_t)tok * 1024 + lane * 16 + k * 4] = res;
  }
}

// ---------------------------------------------------------------------------
extern "C" void kernel_launch(void* const* d_in, const int* in_sizes, int n_in,
                              void* d_out, int out_size, void* d_ws, size_t ws_size,
                              hipStream_t stream) {
  const float* x   = (const float*)d_in[0];
  const float* qw0 = (const float*)d_in[1];
  const float* qw1 = (const float*)d_in[2];
  const float* qw2 = (const float*)d_in[3];
  const float* qb  = (const float*)d_in[4];
  const float* kw0 = (const float*)d_in[5];
  const float* kw1 = (const float*)d_in[6];
  const float* kw2 = (const float*)d_in[7];
  const float* kb  = (const float*)d_in[8];
  const float* vw0 = (const float*)d_in[9];
  const float* vw1 = (const float*)d_in[10];
  const float* vw2 = (const float*)d_in[11];
  const float* vb  = (const float*)d_in[12];
  const float* ow0 = (const float*)d_in[13];
  const float* ow1 = (const float*)d_in[14];
  const float* ow2 = (const float*)d_in[15];
  const float* ob  = (const float*)d_in[16];

  const size_t N = (size_t)NB * NH * S * HD;  // 9,830,400 elems per logical buffer
  _Float16* Qh  = (_Float16*)d_ws;
  _Float16* Kh  = Qh + N;
  _Float16* Vth = Kh + N;
  _Float16* Vh  = Vth + N;            // row-major V temp, later reused as O
  float*    O   = (float*)Vh;
  // total ws use: 3*N*2 + N*4 = 98.3 MB

  tcl_qkv_kernel<<<dim3(NB * S / 4), 256, 0, stream>>>(
      x, qw0, qw1, qw2, qb, kw0, kw1, kw2, kb, vw0, vw1, vw2, vb, Qh, Kh, Vh);
  vtrans_kernel<<<dim3(10, NH, NB), 256, 0, stream>>>(Vh, Vth);
  attn_mfma_kernel<<<dim3(2560), 256, 0, stream>>>(Qh, Kh, Vth, O);
  tcl_out_kernel<<<dim3(NB * S / 4), 256, 0, stream>>>(O, ow0, ow1, ow2, ob,
                                                       (float*)d_out);
}

// Round 9
// 125.369 us; speedup vs baseline: 4.6096x; 1.0106x over previous
//
#include <hip/hip_runtime.h>

// Problem constants:
//   B=16, P1=25, P2=24 -> S=600 tokens; E=(8,8,16)=1024; heads (2,2,4)=16, head_dim 64
#define S   600
#define NB  16
#define NH  16
#define HD  64
// Q pre-scale: (head_dim)^-0.5 * log2(e): scores in log2 domain -> softmax uses exp2.
#define QSCALE 0.18033688011112042f

#define LDT 20   // TCL intermediate row stride (floats)

typedef _Float16 f16x8 __attribute__((ext_vector_type(8)));
typedef float f32x4 __attribute__((ext_vector_type(4)));

// ---------------------------------------------------------------------------
// Kernel A: TCL for q,k,v — wave-per-token, barrier-free.
// ---------------------------------------------------------------------------
__global__ __launch_bounds__(256) void tcl_qkv_kernel(
    const float* __restrict__ x,
    const float* __restrict__ qw0, const float* __restrict__ qw1,
    const float* __restrict__ qw2, const float* __restrict__ qb,
    const float* __restrict__ kw0, const float* __restrict__ kw1,
    const float* __restrict__ kw2, const float* __restrict__ kb,
    const float* __restrict__ vw0, const float* __restrict__ vw1,
    const float* __restrict__ vw2, const float* __restrict__ vb,
    _Float16* __restrict__ Qh, _Float16* __restrict__ Kh,
    _Float16* __restrict__ Vh)
{
  __shared__ __align__(16) float t1s[4][64 * LDT];
  __shared__ __align__(16) float t2s[4][64 * LDT];

  const int tid = threadIdx.x;
  const int wv = tid >> 6, lane = tid & 63;
  const int tok = blockIdx.x * 4 + wv;
  const int b = tok / S, t = tok - b * S;
  const int q = lane >> 3, zp = lane & 7;
  float* __restrict__ t1 = t1s[wv];
  float* __restrict__ t2 = t2s[wv];

  float2 xc[8];
  #pragma unroll
  for (int xx = 0; xx < 8; ++xx)
    xc[xx] = *(const float2*)&x[(size_t)tok * 1024 + xx * 128 + q * 16 + zp * 2];

  const int xs = lane >> 4;
  const int h1 = (lane >> 3) & 1;
  const int cc = lane & 7;
  const int ys = cc >> 1, h2 = cc & 1;

  const float* W0[3] = {qw0, kw0, vw0};
  const float* W1[3] = {qw1, kw1, vw1};
  const float* W2[3] = {qw2, kw2, vw2};
  const float* BB[3] = {qb, kb, vb};
  _Float16* OUT[3] = {Qh, Kh, Vh};

  #pragma unroll
  for (int p = 0; p < 3; ++p) {
    const float* __restrict__ w0 = W0[p];
    const float* __restrict__ w1 = W1[p];
    const float* __restrict__ w2 = W2[p];
    const float* __restrict__ bb = BB[p];
    _Float16* __restrict__ op = OUT[p];

    #pragma unroll
    for (int a = 0; a < 8; ++a) {
      float2 r = make_float2(0.f, 0.f);
      #pragma unroll
      for (int xx = 0; xx < 8; ++xx) {
        const float w = w0[a * 8 + xx];
        r.x = fmaf(w, xc[xx].x, r.x);
        r.y = fmaf(w, xc[xx].y, r.y);
      }
      *(float2*)&t1[(a * 8 + q) * LDT + zp * 2] = r;
    }
    __builtin_amdgcn_wave_barrier();

    float2 t1r[8];
    #pragma unroll
    for (int y = 0; y < 8; ++y)
      t1r[y] = *(float2*)&t1[(q * 8 + y) * LDT + zp * 2];
    #pragma unroll
    for (int c = 0; c < 8; ++c) {
      float2 r = make_float2(0.f, 0.f);
      #pragma unroll
      for (int y = 0; y < 8; ++y) {
        const float w = w1[c * 8 + y];
        r.x = fmaf(w, t1r[y].x, r.x);
        r.y = fmaf(w, t1r[y].y, r.y);
      }
      *(float2*)&t2[(q * 8 + c) * LDT + zp * 2] = r;
    }
    __builtin_amdgcn_wave_barrier();

    float t2r[16];
    #pragma unroll
    for (int k = 0; k < 4; ++k)
      *(float4*)&t2r[k * 4] = *(float4*)&t2[lane * LDT + k * 4];
    float bias[16];
    #pragma unroll
    for (int k = 0; k < 4; ++k)
      *(float4*)&bias[k * 4] = *(const float4*)&bb[lane * 16 + k * 4];
    float o[16];
    #pragma unroll
    for (int d = 0; d < 16; ++d) {
      float acc = 0.f;
      #pragma unroll
      for (int j = 0; j < 16; ++j)
        acc = fmaf(w2[d * 16 + j], t2r[j], acc);
      o[d] = acc + bias[d];
    }
    const float sc = (p == 0) ? QSCALE : 1.0f;
    #pragma unroll
    for (int h3 = 0; h3 < 4; ++h3) {
      union { _Float16 hh[4]; uint2 u; } pk;
      #pragma unroll
      for (int z = 0; z < 4; ++z)
        pk.hh[z] = (_Float16)(o[4 * z + h3] * sc);
      const int head = h1 * 8 + h2 * 4 + h3;
      *(uint2*)&op[((size_t)((b * NH + head) * S + t)) * HD + xs * 16 + ys * 4]
          = pk.u;
    }
    __builtin_amdgcn_wave_barrier();
  }
}

// ---------------------------------------------------------------------------
// Kernel A2: V [b,h,600,64] f16 -> Vt [b,h,64,600] f16.
// ---------------------------------------------------------------------------
__global__ __launch_bounds__(256) void vtrans_kernel(
    const _Float16* __restrict__ Vh, _Float16* __restrict__ Vt)
{
  __shared__ __align__(16) _Float16 tile[64 * 64];
  const int tid = threadIdx.x;
  const int tt = blockIdx.x, h = blockIdx.y, b = blockIdx.z;
  const size_t rbase = (size_t)(b * NH + h) * S * HD;
  const size_t wbase = (size_t)(b * NH + h) * HD * S;
  const int t0 = tt * 64;

  #pragma unroll
  for (int hp = 0; hp < 2; ++hp) {
    const int u = hp * 256 + tid;
    const int r = u >> 3, ch = u & 7;
    f16x8 v = {0, 0, 0, 0, 0, 0, 0, 0};
    if (t0 + r < S) v = *(const f16x8*)&Vh[rbase + (size_t)(t0 + r) * HD + ch * 8];
    *(f16x8*)&tile[r * 64 + ((ch ^ ((r ^ (r >> 3)) & 7)) * 8)] = v;
  }
  __syncthreads();
  #pragma unroll
  for (int hp = 0; hp < 2; ++hp) {
    const int w = hp * 256 + tid;
    const int d = w >> 3, tc = w & 7;
    if (t0 + tc * 8 + 8 <= S) {
      const int cd = d >> 3;
      union { _Float16 hh[8]; f16x8 v; } g;
      #pragma unroll
      for (int e = 0; e < 8; ++e) {
        const int r = tc * 8 + e;
        g.hh[e] = tile[r * 64 + ((cd ^ ((r ^ (r >> 3)) & 7)) * 8) + (d & 7)];
      }
      *(f16x8*)&Vt[wbase + (size_t)d * S + t0 + tc * 8] = g.v;
    }
  }
}

// ---------------------------------------------------------------------------
// Kernel B: MFMA flash attention. Single-buffered K/V (LDS 24 KB -> 6
// blocks/CU, 24 waves). Register-prefetch pipelining; tail-only bounds
// checks; s_setprio(1) around MFMA clusters.
// ---------------------------------------------------------------------------
template<bool TAIL>
__device__ __forceinline__ void attn_step(
    const _Float16* __restrict__ Ks, const _Float16* __restrict__ Vs,
    _Float16* __restrict__ Pw,
    const f16x8 qf0, const f16x8 qf1,
    f32x4 (&po)[4], float& mrow, float& lrow,
    const int lr, const int lg)
{
  constexpr int NMT = TAIL ? 2 : 4;
  f32x4 accs[NMT];
  #pragma unroll
  for (int mt = 0; mt < NMT; ++mt) accs[mt] = (f32x4){0.f, 0.f, 0.f, 0.f};
  __builtin_amdgcn_s_setprio(1);
  #pragma unroll
  for (int c = 0; c < 2; ++c) {
    const f16x8 qf = c ? qf1 : qf0;
    #pragma unroll
    for (int mt = 0; mt < NMT; ++mt) {
      const int krow = mt * 16 + lr;
      const f16x8 kf = *(const f16x8*)
          &Ks[krow * 64 + (((4 * c + lg) ^ (krow & 7)) * 8)];
      accs[mt] = __builtin_amdgcn_mfma_f32_16x16x32_f16(kf, qf, accs[mt], 0, 0, 0);
    }
  }
  __builtin_amdgcn_s_setprio(0);
  float sv[NMT][4];
  #pragma unroll
  for (int mt = 0; mt < NMT; ++mt)
    #pragma unroll
    for (int r = 0; r < 4; ++r) {
      float s = accs[mt][r];
      if (TAIL && mt == 1) s = (lg < 2) ? s : -1e30f;
      sv[mt][r] = s;
    }
  float tmax;
  {
    const float a = fmaxf(fmaxf(sv[0][0], sv[0][1]), fmaxf(sv[0][2], sv[0][3]));
    const float b = fmaxf(fmaxf(sv[1][0], sv[1][1]), fmaxf(sv[1][2], sv[1][3]));
    if (TAIL) {
      tmax = fmaxf(a, b);
    } else {
      const float c2 = fmaxf(fmaxf(sv[2][0], sv[2][1]), fmaxf(sv[2][2], sv[2][3]));
      const float d2 = fmaxf(fmaxf(sv[3][0], sv[3][1]), fmaxf(sv[3][2], sv[3][3]));
      tmax = fmaxf(fmaxf(a, b), fmaxf(c2, d2));
    }
  }
  tmax = fmaxf(tmax, __shfl_xor(tmax, 16));
  tmax = fmaxf(tmax, __shfl_xor(tmax, 32));
  if (!__all(tmax - mrow <= 11.0f)) {
    const float mn = fmaxf(mrow, tmax);
    const float corr = __builtin_amdgcn_exp2f(mrow - mn);
    lrow *= corr;
    #pragma unroll
    for (int dt = 0; dt < 4; ++dt) {
      po[dt][0] *= corr; po[dt][1] *= corr;
      po[dt][2] *= corr; po[dt][3] *= corr;
    }
    mrow = mn;
  }
  _Float16 ph[NMT][4];
  float rsv[NMT];
  #pragma unroll
  for (int mt = 0; mt < NMT; ++mt) {
    const float e0 = __builtin_amdgcn_exp2f(sv[mt][0] - mrow);
    const float e1 = __builtin_amdgcn_exp2f(sv[mt][1] - mrow);
    const float e2 = __builtin_amdgcn_exp2f(sv[mt][2] - mrow);
    const float e3 = __builtin_amdgcn_exp2f(sv[mt][3] - mrow);
    ph[mt][0] = (_Float16)e0; ph[mt][1] = (_Float16)e1;
    ph[mt][2] = (_Float16)e2; ph[mt][3] = (_Float16)e3;
    rsv[mt] = (e0 + e1) + (e2 + e3);
  }
  float rs = TAIL ? (rsv[0] + rsv[1]) : ((rsv[0] + rsv[1]) + (rsv[2] + rsv[3]));
  rs += __shfl_xor(rs, 16);
  rs += __shfl_xor(rs, 32);
  lrow += rs;
  #pragma unroll
  for (int mt = 0; mt < NMT; ++mt) {
    union { _Float16 hh[4]; unsigned long long u; } pk;
    pk.hh[0] = ph[mt][0]; pk.hh[1] = ph[mt][1];
    pk.hh[2] = ph[mt][2]; pk.hh[3] = ph[mt][3];
    const int idx = lr * 64 + (((2 * mt + (lg >> 1)) ^ (lr & 7)) * 8)
                  + (lg & 1) * 4;
    *(unsigned long long*)&Pw[idx] = pk.u;
  }
  __builtin_amdgcn_wave_barrier();   // fence: P writes before P reads (same wave)
  __builtin_amdgcn_s_setprio(1);
  #pragma unroll
  for (int c = 0; c < (TAIL ? 1 : 2); ++c) {
    const f16x8 pf = *(const f16x8*)&Pw[lr * 64 + (((4 * c + lg) ^ (lr & 7)) * 8)];
    #pragma unroll
    for (int dt = 0; dt < 4; ++dt) {
      const int drow = dt * 16 + lr;
      const f16x8 vf = *(const f16x8*)
          &Vs[drow * 64 + (((4 * c + lg) ^ (drow & 7)) * 8)];
      po[dt] = __builtin_amdgcn_mfma_f32_16x16x32_f16(vf, pf, po[dt], 0, 0, 0);
    }
  }
  __builtin_amdgcn_s_setprio(0);
}

__global__ __launch_bounds__(256) void attn_mfma_kernel(
    const _Float16* __restrict__ Qh, const _Float16* __restrict__ Kh,
    const _Float16* __restrict__ Vt, float* __restrict__ Og)
{
  __shared__ __align__(16) union {
    struct {
      _Float16 K[64 * 64];      // swizzled [key][d]       8 KB
      _Float16 V[64 * 64];      // swizzled [d][key]       8 KB
      _Float16 P[4][16 * 64];   // per-wave P relay        8 KB
    } m;                        // 24576 B -> 6 blocks/CU
    float ot[4][64 * 17];       // epilogue staging (17408 B)
  } sm;

  const int tid = threadIdx.x;
  const int lane = tid & 63;
  const int wv = tid >> 6;
  // XCD-aware decode: all 10 q-tiles of a (b,h) co-locate on one XCD.
  const int id = blockIdx.x;
  const int idx = id >> 3;
  const int bh = (id & 7) * 32 + idx / 10;
  const int qt = idx - (idx / 10) * 10;
  const size_t base  = (size_t)bh * S * HD;
  const size_t vbase = (size_t)bh * HD * S;
  const int lr = lane & 15;
  const int lg = lane >> 4;

  const int qrow_l = qt * 64 + wv * 16 + lr;
  const int qrow = (qrow_l < S) ? qrow_l : (S - 1);
  const f16x8 qf0 = *(const f16x8*)&Qh[base + (size_t)qrow * HD + lg * 8];
  const f16x8 qf1 = *(const f16x8*)&Qh[base + (size_t)qrow * HD + 32 + lg * 8];

  f32x4 po[4] = {{0.f,0.f,0.f,0.f},{0.f,0.f,0.f,0.f},
                 {0.f,0.f,0.f,0.f},{0.f,0.f,0.f,0.f}};
  float mrow = -1e30f, lrow = 0.f;

  const int srow = tid >> 3, sch = tid & 7;   // staging: row 0..31, 16B chunk
  const int srow2 = srow + 32;                 // rows 32..63
  const int sswz = ((sch ^ (srow & 7)) * 8);   // srow2&7 == srow&7

  f16x8 kv[2], vv[2];
  auto stage_load_full = [&](int kt) {         // tiles 0..8: no bounds checks
    const int kb = kt * 64;
    kv[0] = *(const f16x8*)&Kh[base + (size_t)(kb + srow ) * HD + sch * 8];
    kv[1] = *(const f16x8*)&Kh[base + (size_t)(kb + srow2) * HD + sch * 8];
    vv[0] = *(const f16x8*)&Vt[vbase + (size_t)srow  * S + kb + sch * 8];
    vv[1] = *(const f16x8*)&Vt[vbase + (size_t)srow2 * S + kb + sch * 8];
  };
  auto stage_load_tail = [&]() {               // kt=9: keys 576..599 valid
    const int kb = 576;
    const f16x8 z = {0, 0, 0, 0, 0, 0, 0, 0};
    kv[0] = (srow < 24)
        ? *(const f16x8*)&Kh[base + (size_t)(kb + srow) * HD + sch * 8] : z;
    kv[1] = z;                                 // rows 32..63 all dead
    if (sch < 3) {                             // key chunks 576..599 (600%8==0)
      vv[0] = *(const f16x8*)&Vt[vbase + (size_t)srow  * S + kb + sch * 8];
      vv[1] = *(const f16x8*)&Vt[vbase + (size_t)srow2 * S + kb + sch * 8];
    } else { vv[0] = z; vv[1] = z; }
  };
  auto stage_write = [&]() {
    *(f16x8*)&sm.m.K[srow  * 64 + sswz] = kv[0];
    *(f16x8*)&sm.m.K[srow2 * 64 + sswz] = kv[1];
    *(f16x8*)&sm.m.V[srow  * 64 + sswz] = vv[0];
    *(f16x8*)&sm.m.V[srow2 * 64 + sswz] = vv[1];
  };

  stage_load_full(0);
  #pragma unroll 1
  for (int kt = 0; kt < 9; ++kt) {
    __syncthreads();                  // prior tile's LDS reads complete
    stage_write();
    if (kt < 8) stage_load_full(kt + 1);   // next loads in flight over compute
    else        stage_load_tail();
    __syncthreads();                  // K/V visible to all waves
    attn_step<false>(&sm.m.K[0], &sm.m.V[0], &sm.m.P[wv][0],
                     qf0, qf1, po, mrow, lrow, lr, lg);
  }
  __syncthreads();
  stage_write();
  __syncthreads();
  attn_step<true>(&sm.m.K[0], &sm.m.V[0], &sm.m.P[wv][0],
                  qf0, qf1, po, mrow, lrow, lr, lg);
  __syncthreads();   // main-loop LDS fully consumed before epilogue reuse

  const float invl = 1.0f / lrow;
  #pragma unroll
  for (int dt = 0; dt < 4; ++dt)
    #pragma unroll
    for (int r = 0; r < 4; ++r)
      sm.ot[wv][(dt * 16 + 4 * lg + r) * 17 + lr] = po[dt][r] * invl;
  __builtin_amdgcn_wave_barrier();   // fence: ot writes before ot reads (same wave)
  #pragma unroll
  for (int ps = 0; ps < 4; ++ps) {
    const int qr = ps * 4 + lg;
    const int gq = qt * 64 + wv * 16 + qr;
    if (gq < S) {
      const int d0 = lr * 4;
      float4 o4;
      o4.x = sm.ot[wv][(d0 + 0) * 17 + qr];
      o4.y = sm.ot[wv][(d0 + 1) * 17 + qr];
      o4.z = sm.ot[wv][(d0 + 2) * 17 + qr];
      o4.w = sm.ot[wv][(d0 + 3) * 17 + qr];
      *(float4*)&Og[base + (size_t)gq * HD + d0] = o4;
    }
  }
}

// ---------------------------------------------------------------------------
// Kernel C: output TCL — wave-per-token, barrier-free.
// ---------------------------------------------------------------------------
__global__ __launch_bounds__(256) void tcl_out_kernel(
    const float* __restrict__ Og,
    const float* __restrict__ ow0, const float* __restrict__ ow1,
    const float* __restrict__ ow2, const float* __restrict__ ob,
    float* __restrict__ out)
{
  __shared__ __align__(16) float t1s[4][64 * LDT];
  __shared__ __align__(16) float t2s[4][64 * LDT];

  const int tid = threadIdx.x;
  const int wv = tid >> 6, lane = tid & 63;
  const int tok = blockIdx.x * 4 + wv;
  const int b = tok / S, t = tok - b * S;
  const int q = lane >> 3, zp = lane & 7;
  float* __restrict__ t1 = t1s[wv];
  float* __restrict__ t2 = t2s[wv];

  float2 xc[8];
  {
    const int h2g = q & 1, yg = q >> 1;
    const int h3g = 2 * (zp & 1), zg = zp >> 1;
    #pragma unroll
    for (int xx = 0; xx < 8; ++xx) {
      const int headb = (xx & 1) * 8 + h2g * 4 + h3g;
      const size_t off = ((size_t)((b * NH + headb) * S + t)) * HD
                       + (xx >> 1) * 16 + yg * 4 + zg;
      xc[xx].x = Og[off];
      xc[xx].y = Og[off + (size_t)S * HD];
    }
  }

  #pragma unroll
  for (int a = 0; a < 8; ++a) {
    float2 r = make_float2(0.f, 0.f);
    #pragma unroll
    for (int xx = 0; xx < 8; ++xx) {
      const float w = ow0[a * 8 + xx];
      r.x = fmaf(w, xc[xx].x, r.x);
      r.y = fmaf(w, xc[xx].y, r.y);
    }
    *(float2*)&t1[(a * 8 + q) * LDT + zp * 2] = r;
  }
  __builtin_amdgcn_wave_barrier();

  float2 t1r[8];
  #pragma unroll
  for (int y = 0; y < 8; ++y)
    t1r[y] = *(float2*)&t1[(q * 8 + y) * LDT + zp * 2];
  #pragma unroll
  for (int c = 0; c < 8; ++c) {
    float2 r = make_float2(0.f, 0.f);
    #pragma unroll
    for (int y = 0; y < 8; ++y) {
      const float w = ow1[c * 8 + y];
      r.x = fmaf(w, t1r[y].x, r.x);
      r.y = fmaf(w, t1r[y].y, r.y);
    }
    *(float2*)&t2[(q * 8 + c) * LDT + zp * 2] = r;
  }
  __builtin_amdgcn_wave_barrier();

  float t2r[16];
  #pragma unroll
  for (int k = 0; k < 4; ++k)
    *(float4*)&t2r[k * 4] = *(float4*)&t2[lane * LDT + k * 4];
  float bias[16];
  #pragma unroll
  for (int k = 0; k < 4; ++k)
    *(float4*)&bias[k * 4] = *(const float4*)&ob[lane * 16 + k * 4];
  float o[16];
  #pragma unroll
  for (int d = 0; d < 16; ++d) {
    float acc = 0.f;
    #pragma unroll
    for (int j = 0; j < 16; ++j)
      acc = fmaf(ow2[d * 16 + j], t2r[j], acc);
    o[d] = acc + bias[d];
  }
  #pragma unroll
  for (int k = 0; k < 4; ++k) {
    const float4 res = make_float4(o[4 * k], o[4 * k + 1],
                                   o[4 * k + 2], o[4 * k + 3]);
    *(float4*)&out[(size_t)tok * 1024 + lane * 16 + k * 4] = res;
  }
}

// ---------------------------------------------------------------------------
extern "C" void kernel_launch(void* const* d_in, const int* in_sizes, int n_in,
                              void* d_out, int out_size, void* d_ws, size_t ws_size,
                              hipStream_t stream) {
  const float* x   = (const float*)d_in[0];
  const float* qw0 = (const float*)d_in[1];
  const float* qw1 = (const float*)d_in[2];
  const float* qw2 = (const float*)d_in[3];
  const float* qb  = (const float*)d_in[4];
  const float* kw0 = (const float*)d_in[5];
  const float* kw1 = (const float*)d_in[6];
  const float* kw2 = (const float*)d_in[7];
  const float* kb  = (const float*)d_in[8];
  const float* vw0 = (const float*)d_in[9];
  const float* vw1 = (const float*)d_in[10];
  const float* vw2 = (const float*)d_in[11];
  const float* vb  = (const float*)d_in[12];
  const float* ow0 = (const float*)d_in[13];
  const float* ow1 = (const float*)d_in[14];
  const float* ow2 = (const float*)d_in[15];
  const float* ob  = (const float*)d_in[16];

  const size_t N = (size_t)NB * NH * S * HD;  // 9,830,400 elems per logical buffer
  _Float16* Qh  = (_Float16*)d_ws;
  _Float16* Kh  = Qh + N;
  _Float16* Vth = Kh + N;
  _Float16* Vh  = Vth + N;            // row-major V temp, later reused as O
  float*    O   = (float*)Vh;
  // total ws use: 3*N*2 + N*4 = 98.3 MB

  tcl_qkv_kernel<<<dim3(NB * S / 4), 256, 0, stream>>>(
      x, qw0, qw1, qw2, qb, kw0, kw1, kw2, kb, vw0, vw1, vw2, vb, Qh, Kh, Vh);
  vtrans_kernel<<<dim3(10, NH, NB), 256, 0, stream>>>(Vh, Vth);
  attn_mfma_kernel<<<dim3(2560), 256, 0, stream>>>(Qh, Kh, Vth, O);
  tcl_out_kernel<<<dim3(NB * S / 4), 256, 0, stream>>>(O, ow0, ow1, ow2, ob,
                                                       (float*)d_out);
}